// Round 5
// baseline (307.854 us; speedup 1.0000x reference)
//
#include <hip/hip_runtime.h>

typedef __attribute__((ext_vector_type(8))) short bf16x8;
typedef __attribute__((ext_vector_type(4))) float f32x4;

#define MFMA16(a, b, c) __builtin_amdgcn_mfma_f32_16x16x32_bf16(a, b, c, 0, 0, 0)

__device__ inline short f2bf(float f) {
  union { float f; unsigned u; } v;
  v.f = f;
  unsigned r = v.u + 0x7FFF + ((v.u >> 16) & 1);
  return (short)(r >> 16);
}
__device__ inline float bf2f(short s) {
  union { unsigned u; float f; } v;
  v.u = ((unsigned)(unsigned short)s) << 16;
  return v.f;
}
#define GLD_LDS16(g, l)                                                        \
  __builtin_amdgcn_global_load_lds(                                            \
      (const __attribute__((address_space(1))) unsigned int*)(g),              \
      (__attribute__((address_space(3))) unsigned int*)(l), 16, 0, 0)

// ---------------- convert fp32 -> bf16 ----------------
__global__ __launch_bounds__(256) void cvt_kernel(const float* __restrict__ src,
                                                  short* __restrict__ dst, int n) {
  int i = (blockIdx.x * 256 + threadIdx.x) * 4;
  if (i >= n) return;
  float4 f = *(const float4*)&src[i];
  short4 o;
  o.x = f2bf(f.x); o.y = f2bf(f.y); o.z = f2bf(f.z); o.w = f2bf(f.w);
  *(short4*)&dst[i] = o;
}

// ---------------- all 4 weight transposes in ONE launch ----------------
// q_w(2048x2048)->wqkv_t[0:2048], k_w(2048x256)->wqkv_t[2048:2304],
// v_w(2048x256)->wqkv_t[2304:2560], o_w(2048x2048)->wo_t
__global__ __launch_bounds__(256) void tconv_all_kernel(
    const float* __restrict__ q_w, const float* __restrict__ k_w,
    const float* __restrict__ v_w, const float* __restrict__ o_w,
    short* __restrict__ wqkv_t, short* __restrict__ wo_t) {
  __shared__ float t[64][65];
  int bid = blockIdx.x;
  const float* src;
  short* dst;
  int C, bx, by;
  if (bid < 1024) {
    src = q_w; dst = wqkv_t; C = 2048;
    bx = (bid & 31) * 64; by = (bid >> 5) * 64;
  } else if (bid < 1152) {
    bid -= 1024;
    src = k_w; dst = wqkv_t + (size_t)2048 * 2048; C = 256;
    bx = (bid & 3) * 64; by = (bid >> 2) * 64;
  } else if (bid < 1280) {
    bid -= 1152;
    src = v_w; dst = wqkv_t + (size_t)2304 * 2048; C = 256;
    bx = (bid & 3) * 64; by = (bid >> 2) * 64;
  } else {
    bid -= 1280;
    src = o_w; dst = wo_t; C = 2048;
    bx = (bid & 31) * 64; by = (bid >> 5) * 64;
  }
  const int R = 2048;
  const int tx = threadIdx.x & 15;
  const int ty = threadIdx.x >> 4;
#pragma unroll
  for (int i = 0; i < 4; i++) {
    int row = ty + i * 16;
    float4 f = *(const float4*)&src[(size_t)(by + row) * C + bx + tx * 4];
    t[row][tx * 4 + 0] = f.x;
    t[row][tx * 4 + 1] = f.y;
    t[row][tx * 4 + 2] = f.z;
    t[row][tx * 4 + 3] = f.w;
  }
  __syncthreads();
#pragma unroll
  for (int i = 0; i < 4; i++) {
    int c = ty + i * 16;
    short4 o;
    o.x = f2bf(t[tx * 4 + 0][c]);
    o.y = f2bf(t[tx * 4 + 1][c]);
    o.z = f2bf(t[tx * 4 + 2][c]);
    o.w = f2bf(t[tx * 4 + 3][c]);
    *(short4*)&dst[(size_t)(bx + c) * R + by + tx * 4] = o;
  }
}

// ---------------- QKV GEMM with FUSED bias+rmsnorm+rope+mask epilogue ----------------
// A = x bf16 (2048 x 2048), B = wqkv_t (2560 x 2048). grid (20,16).
// col tile n0: <2048 q head n0/128; <2304 k head; else v head.
__global__ __launch_bounds__(256) void gemm_qkv_kernel(
    const short* __restrict__ A, const short* __restrict__ B,
    const float* __restrict__ qbias, const float* __restrict__ kbias,
    const float* __restrict__ vbias, const float* __restrict__ qg,
    const float* __restrict__ kg, const float* __restrict__ cosb,
    const float* __restrict__ sinb, const float* __restrict__ maskp,
    short* __restrict__ qo, short* __restrict__ ko, short* __restrict__ vo) {
  __shared__ __align__(16) char smem[33792];
  short* As = (short*)smem;
  short* Bs = (short*)(smem + 8192);
  const int tid = threadIdx.x;
  const int lane = tid & 63, wave = tid >> 6;
  const int quad = lane >> 4, l16 = lane & 15;
  const int m0 = blockIdx.y * 128, n0 = blockIdx.x * 128;
  const int wm = (wave >> 1) * 64, wn = (wave & 1) * 64;
  f32x4 acc[4][4];
#pragma unroll
  for (int mi = 0; mi < 4; mi++)
#pragma unroll
    for (int ni = 0; ni < 4; ni++) acc[mi][ni] = (f32x4){0.f, 0.f, 0.f, 0.f};

  for (int k0 = 0; k0 < 2048; k0 += 32) {
#pragma unroll
    for (int it = 0; it < 2; it++) {
      int c = it * 256 + tid;
      int row = c >> 2, cc = (c & 3) * 8;
      GLD_LDS16(&A[(size_t)(m0 + row) * 2048 + k0 + cc], &As[c * 8]);
      GLD_LDS16(&B[(size_t)(n0 + row) * 2048 + k0 + cc], &Bs[c * 8]);
    }
    __syncthreads();
    bf16x8 af[4], bfr[4];
#pragma unroll
    for (int mi = 0; mi < 4; mi++)
      af[mi] = *(const bf16x8*)&As[(wm + mi * 16 + l16) * 32 + quad * 8];
#pragma unroll
    for (int ni = 0; ni < 4; ni++)
      bfr[ni] = *(const bf16x8*)&Bs[(wn + ni * 16 + l16) * 32 + quad * 8];
#pragma unroll
    for (int mi = 0; mi < 4; mi++)
#pragma unroll
      for (int ni = 0; ni < 4; ni++)
        acc[mi][ni] = MFMA16(af[mi], bfr[ni], acc[mi][ni]);
    __syncthreads();
  }

  // ---- fused epilogue ----
  const int type = (n0 < 2048) ? 0 : (n0 < 2304) ? 1 : 2;  // q/k/v
  // bias per column
  float bcol[4];
#pragma unroll
  for (int ni = 0; ni < 4; ni++) {
    int cg = n0 + wn + ni * 16 + l16;
    bcol[ni] = (type == 0) ? qbias[cg] : (type == 1) ? kbias[cg - 2048] : vbias[cg - 2304];
  }
#pragma unroll
  for (int mi = 0; mi < 4; mi++)
#pragma unroll
    for (int ni = 0; ni < 4; ni++)
#pragma unroll
      for (int r = 0; r < 4; r++) acc[mi][ni][r] += bcol[ni];

  if (type == 2) {  // V: mask + store bf16 (b,kv,s,d)
    const int kvh = (n0 - 2304) >> 7;
#pragma unroll
    for (int mi = 0; mi < 4; mi++)
#pragma unroll
      for (int r = 0; r < 4; r++) {
        int row = m0 + wm + mi * 16 + quad * 4 + r;
        int b = row >> 10, s = row & 1023;
        float mk = maskp[row];
#pragma unroll
        for (int ni = 0; ni < 4; ni++) {
          int d = wn + ni * 16 + l16;
          vo[(((size_t)(b * 2 + kvh) * 1024) + s) * 128 + d] = f2bf(acc[mi][ni][r] * mk);
        }
      }
    return;
  }

  // Q/K: rmsnorm over 128 cols (wave pair w, w^1 share rows)
  short* ex = (short*)smem;              // [4][64][64] bf16
  float* red = (float*)(smem + 32768);   // [4][64]
#pragma unroll
  for (int mi = 0; mi < 4; mi++)
#pragma unroll
    for (int r = 0; r < 4; r++) {
      float ss = 0.f;
#pragma unroll
      for (int ni = 0; ni < 4; ni++) ss += acc[mi][ni][r] * acc[mi][ni][r];
#pragma unroll
      for (int off = 1; off < 16; off <<= 1) ss += __shfl_xor(ss, off);
      if (l16 == 0) red[wave * 64 + mi * 16 + quad * 4 + r] = ss;
    }
  __syncthreads();
  const float* gamma = (type == 0) ? qg : kg;
  float gcol[4];
#pragma unroll
  for (int ni = 0; ni < 4; ni++) gcol[ni] = gamma[wn + ni * 16 + l16];
#pragma unroll
  for (int mi = 0; mi < 4; mi++)
#pragma unroll
    for (int r = 0; r < 4; r++) {
      int row64 = mi * 16 + quad * 4 + r;
      float tot = red[wave * 64 + row64] + red[(wave ^ 1) * 64 + row64];
      float rq = rsqrtf(tot * (1.0f / 128.0f) + 1e-6f);
#pragma unroll
      for (int ni = 0; ni < 4; ni++) {
        float nv = acc[mi][ni][r] * rq * gcol[ni];
        acc[mi][ni][r] = nv;
        ex[wave * 4096 + row64 * 64 + ni * 16 + l16] = f2bf(nv);
      }
    }
  __syncthreads();
  const int h = (type == 0) ? (n0 >> 7) : ((n0 - 2048) >> 7);
#pragma unroll
  for (int mi = 0; mi < 4; mi++)
#pragma unroll
    for (int r = 0; r < 4; r++) {
      int row64 = mi * 16 + quad * 4 + r;
      int row = m0 + wm + row64;
      int b = row >> 10, s = row & 1023;
      float mk = (type == 1) ? maskp[row] : 1.f;
#pragma unroll
      for (int ni = 0; ni < 4; ni++) {
        int d = wn + ni * 16 + l16;
        float partner = bf2f(ex[(wave ^ 1) * 4096 + row64 * 64 + ni * 16 + l16]);
        int dm = d & 63;
        int sel = (dm < 16) ? 0 : (dm < 40) ? 1 : 2;
        size_t ci = ((size_t)(sel * 2 + b) * 1024 + s) * 128 + d;
        float c = cosb[ci], sn = sinb[ci];
        float outv = wn ? (acc[mi][ni][r] * c + partner * sn)
                        : (acc[mi][ni][r] * c - partner * sn);
        outv *= mk;
        if (type == 0)
          qo[(((size_t)(b * 16 + h) * 1024) + s) * 128 + d] = f2bf(outv);
        else
          ko[(((size_t)(b * 2 + h) * 1024) + s) * 128 + d] = f2bf(outv);
      }
    }
}

// ---------------- plain bf16 GEMM (for out-proj), split-K via C0/C1 ----------------
__global__ __launch_bounds__(256) void gemm_kernel(const short* __restrict__ A,
                                                   const short* __restrict__ B,
                                                   float* __restrict__ C0,
                                                   float* __restrict__ C1,
                                                   int lda, int ldb, int N, int Klen) {
  __shared__ __align__(16) short As[128 * 32];
  __shared__ __align__(16) short Bs[128 * 32];
  const int tid = threadIdx.x;
  const int lane = tid & 63, wave = tid >> 6;
  const int quad = lane >> 4, l16 = lane & 15;
  const int m0 = blockIdx.y * 128, n0 = blockIdx.x * 128;
  const int kz = blockIdx.z;
  const short* Ap = A + (size_t)kz * Klen;
  const short* Bp = B + (size_t)kz * Klen;
  float* C = kz ? C1 : C0;
  const int wm = (wave >> 1) * 64, wn = (wave & 1) * 64;
  f32x4 acc[4][4];
#pragma unroll
  for (int mi = 0; mi < 4; mi++)
#pragma unroll
    for (int ni = 0; ni < 4; ni++) acc[mi][ni] = (f32x4){0.f, 0.f, 0.f, 0.f};

  for (int k0 = 0; k0 < Klen; k0 += 32) {
#pragma unroll
    for (int it = 0; it < 2; it++) {
      int c = it * 256 + tid;
      int row = c >> 2, cc = (c & 3) * 8;
      GLD_LDS16(&Ap[(size_t)(m0 + row) * lda + k0 + cc], &As[c * 8]);
      GLD_LDS16(&Bp[(size_t)(n0 + row) * ldb + k0 + cc], &Bs[c * 8]);
    }
    __syncthreads();
    bf16x8 af[4], bfr[4];
#pragma unroll
    for (int mi = 0; mi < 4; mi++)
      af[mi] = *(const bf16x8*)&As[(wm + mi * 16 + l16) * 32 + quad * 8];
#pragma unroll
    for (int ni = 0; ni < 4; ni++)
      bfr[ni] = *(const bf16x8*)&Bs[(wn + ni * 16 + l16) * 32 + quad * 8];
#pragma unroll
    for (int mi = 0; mi < 4; mi++)
#pragma unroll
      for (int ni = 0; ni < 4; ni++)
        acc[mi][ni] = MFMA16(af[mi], bfr[ni], acc[mi][ni]);
    __syncthreads();
  }
#pragma unroll
  for (int mi = 0; mi < 4; mi++)
#pragma unroll
    for (int ni = 0; ni < 4; ni++)
#pragma unroll
      for (int r = 0; r < 4; r++)
        C[(size_t)(m0 + wm + mi * 16 + quad * 4 + r) * N + n0 + wn + ni * 16 + l16] =
            acc[mi][ni][r];
}

// ---------------- out = out + part ----------------
__global__ __launch_bounds__(256) void addf_kernel(float* __restrict__ out,
                                                   const float* __restrict__ part) {
  int i = (blockIdx.x * 256 + threadIdx.x) * 4;
  float4 a = *(float4*)&out[i];
  float4 b = *(const float4*)&part[i];
  a.x += b.x; a.y += b.y; a.z += b.z; a.w += b.w;
  *(float4*)&out[i] = a;
}

// ---------------- V bf16 transpose: (b,kv,s,d) -> (b,kv,d,s) ----------------
__global__ __launch_bounds__(256) void vtrans16_kernel(const short* __restrict__ vb,
                                                       short* __restrict__ vtb) {
  __shared__ short t[64][65];
  const int bz = blockIdx.z;
  const int d0 = blockIdx.x * 64, s0 = blockIdx.y * 64;
  const int tx = threadIdx.x & 15;
  const int ty = threadIdx.x >> 4;
#pragma unroll
  for (int i = 0; i < 4; i++) {
    int row = ty + i * 16;
    short4 v = *(const short4*)&vb[((size_t)bz * 1024 + s0 + row) * 128 + d0 + tx * 4];
    t[row][tx * 4 + 0] = v.x;
    t[row][tx * 4 + 1] = v.y;
    t[row][tx * 4 + 2] = v.z;
    t[row][tx * 4 + 3] = v.w;
  }
  __syncthreads();
#pragma unroll
  for (int i = 0; i < 4; i++) {
    int c = ty + i * 16;
    short4 o;
    o.x = t[tx * 4 + 0][c];
    o.y = t[tx * 4 + 1][c];
    o.z = t[tx * 4 + 2][c];
    o.w = t[tx * 4 + 3][c];
    *(short4*)&vtb[((size_t)bz * 128 + d0 + c) * 1024 + s0 + tx * 4] = o;
  }
}

// ---------------- flash attention, key-chunk split (chunk = 256 keys, <=4 steps) ----------------
__global__ __launch_bounds__(256) void attn_kernel(const short* __restrict__ Q,
                                                   const short* __restrict__ K,
                                                   const short* __restrict__ Vt_g,
                                                   short* __restrict__ po,
                                                   float* __restrict__ pml) {
  int x = blockIdx.x;
  const int h = blockIdx.y;
  const int b = blockIdx.z;
  int g = 0, base = 0;
  while (x >= base + 4 * (g + 1)) { base += 4 * (g + 1); g++; }
  const int r0 = x - base;
  const int qt = 4 * g + r0 / (g + 1);
  const int kc = r0 % (g + 1);
  int nsteps = qt - 4 * kc + 1;
  if (nsteps > 4) nsteps = 4;

  const int kv = h >> 3;
  const int tid = threadIdx.x;
  const int wave = tid >> 6, lane = tid & 63;
  const int quad = lane >> 4, l16 = lane & 15;
  __shared__ __align__(16) short Ks[64 * 136];
  __shared__ __align__(16) short Vs[128 * 72];
  __shared__ __align__(16) short Ps[4][16 * 68];

  const size_t qoff = (((size_t)(b * 16 + h) * 1024) + qt * 64 + wave * 16 + l16) * 128;
  bf16x8 aq[4];
#pragma unroll
  for (int kk = 0; kk < 4; kk++) aq[kk] = *(const bf16x8*)&Q[qoff + kk * 32 + quad * 8];

  f32x4 o[8];
#pragma unroll
  for (int i = 0; i < 8; i++) o[i] = (f32x4){0.f, 0.f, 0.f, 0.f};
  float m[4], l[4];
#pragma unroll
  for (int r = 0; r < 4; r++) { m[r] = -1e30f; l[r] = 0.f; }
  const int qrow0 = qt * 64 + wave * 16 + quad * 4;
  const size_t koff = ((size_t)(b * 2 + kv) * 1024) * 128;
  const size_t voff = koff;
  const float scale = 0.08838834764831845f;

  for (int st = 0; st < nsteps; st++) {
    const int ks0 = kc * 256 + st * 64;
#pragma unroll
    for (int it = 0; it < 4; it++) {
      int c = it * 256 + tid;
      {
        int row = c >> 4, cc = (c & 15) * 8;
        *(int4*)&Ks[row * 136 + cc] =
            *(const int4*)&K[koff + (size_t)(ks0 + row) * 128 + cc];
      }
      {
        int d = c >> 3, cc = (c & 7) * 8;
        *(int4*)&Vs[d * 72 + cc] =
            *(const int4*)&Vt_g[voff + (size_t)d * 1024 + ks0 + cc];
      }
    }
    __syncthreads();
    f32x4 sc[4];
#pragma unroll
    for (int nt = 0; nt < 4; nt++) sc[nt] = (f32x4){0.f, 0.f, 0.f, 0.f};
#pragma unroll
    for (int nt = 0; nt < 4; nt++)
#pragma unroll
      for (int kk = 0; kk < 4; kk++) {
        bf16x8 bk = *(const bf16x8*)&Ks[(nt * 16 + l16) * 136 + kk * 32 + quad * 8];
        sc[nt] = MFMA16(aq[kk], bk, sc[nt]);
      }
    float sv[4][4], mx[4];
#pragma unroll
    for (int r = 0; r < 4; r++) mx[r] = -1e30f;
#pragma unroll
    for (int nt = 0; nt < 4; nt++)
#pragma unroll
      for (int r = 0; r < 4; r++) {
        float s = sc[nt][r] * scale;
        int kcol = ks0 + nt * 16 + l16;
        if (kcol > qrow0 + r) s = -1e30f;
        sv[nt][r] = s;
        mx[r] = fmaxf(mx[r], s);
      }
#pragma unroll
    for (int off = 1; off < 16; off <<= 1)
#pragma unroll
      for (int r = 0; r < 4; r++) mx[r] = fmaxf(mx[r], __shfl_xor(mx[r], off));
    float alpha[4];
#pragma unroll
    for (int r = 0; r < 4; r++) {
      float mn = fmaxf(m[r], mx[r]);
      alpha[r] = __expf(m[r] - mn);
      m[r] = mn;
    }
    float rs[4] = {0.f, 0.f, 0.f, 0.f};
#pragma unroll
    for (int nt = 0; nt < 4; nt++)
#pragma unroll
      for (int r = 0; r < 4; r++) {
        float p = __expf(sv[nt][r] - m[r]);
        sv[nt][r] = p;
        rs[r] += p;
      }
#pragma unroll
    for (int r = 0; r < 4; r++) l[r] = l[r] * alpha[r] + rs[r];
#pragma unroll
    for (int i = 0; i < 8; i++)
#pragma unroll
      for (int r = 0; r < 4; r++) o[i][r] *= alpha[r];
    short* P = &Ps[wave][0];
#pragma unroll
    for (int nt = 0; nt < 4; nt++)
#pragma unroll
      for (int r = 0; r < 4; r++)
        P[(quad * 4 + r) * 68 + nt * 16 + l16] = f2bf(sv[nt][r]);
    __asm__ volatile("s_waitcnt lgkmcnt(0)" ::: "memory");
    bf16x8 pa0 = *(const bf16x8*)&P[l16 * 68 + quad * 8];
    bf16x8 pa1 = *(const bf16x8*)&P[l16 * 68 + 32 + quad * 8];
#pragma unroll
    for (int nt = 0; nt < 8; nt++) {
      bf16x8 bv0 = *(const bf16x8*)&Vs[(nt * 16 + l16) * 72 + quad * 8];
      bf16x8 bv1 = *(const bf16x8*)&Vs[(nt * 16 + l16) * 72 + 32 + quad * 8];
      o[nt] = MFMA16(pa0, bv0, o[nt]);
      o[nt] = MFMA16(pa1, bv1, o[nt]);
    }
    __syncthreads();
  }
#pragma unroll
  for (int off = 1; off < 16; off <<= 1)
#pragma unroll
    for (int r = 0; r < 4; r++) l[r] += __shfl_xor(l[r], off);
  const int p = (b * 16 + h) * 40 + blockIdx.x;
  const int lrow = wave * 16 + quad * 4;
#pragma unroll
  for (int nt = 0; nt < 8; nt++)
#pragma unroll
    for (int r = 0; r < 4; r++)
      po[(size_t)p * 8192 + (size_t)(lrow + r) * 128 + nt * 16 + l16] = f2bf(o[nt][r]);
  if (l16 == 0) {
#pragma unroll
    for (int r = 0; r < 4; r++) {
      pml[(size_t)p * 128 + lrow + r] = m[r];
      pml[(size_t)p * 128 + 64 + lrow + r] = l[r];
    }
  }
}

// ---------------- combine partials -> attn output (b*S, NH*HD) bf16 ----------------
__global__ __launch_bounds__(256) void attn_combine_kernel(const short* __restrict__ po,
                                                           const float* __restrict__ pml,
                                                           short* __restrict__ attn) {
  const int qt = blockIdx.x, h = blockIdx.y, b = blockIdx.z;
  const int g = qt >> 2, nc = g + 1;
  const int x0 = 2 * g * (g + 1) + (qt & 3) * nc;
  const int row = threadIdx.x >> 2;
  const int d0 = (threadIdx.x & 3) * 32;
  const int pbase = (b * 16 + h) * 40 + x0;
  float mm[4], ll[4], M = -1e30f;
#pragma unroll
  for (int kc = 0; kc < 4; kc++)
    if (kc < nc) {
      mm[kc] = pml[(size_t)(pbase + kc) * 128 + row];
      ll[kc] = pml[(size_t)(pbase + kc) * 128 + 64 + row];
      M = fmaxf(M, mm[kc]);
    }
  float denom = 0.f, sc[4];
#pragma unroll
  for (int kc = 0; kc < 4; kc++)
    if (kc < nc) { sc[kc] = __expf(mm[kc] - M); denom += sc[kc] * ll[kc]; }
  float inv = 1.f / denom;
  float acc[32];
#pragma unroll
  for (int j = 0; j < 32; j++) acc[j] = 0.f;
#pragma unroll
  for (int kc = 0; kc < 4; kc++)
    if (kc < nc) {
      const short* src = po + (size_t)(pbase + kc) * 8192 + (size_t)row * 128 + d0;
#pragma unroll
      for (int j = 0; j < 4; j++) {
        int4 v = *(const int4*)&src[j * 8];
        const short* vs = (const short*)&v;
#pragma unroll
        for (int e = 0; e < 8; e++) acc[j * 8 + e] += sc[kc] * bf2f(vs[e]);
      }
    }
  short ob[32];
#pragma unroll
  for (int j = 0; j < 32; j++) ob[j] = f2bf(acc[j] * inv);
  short* dst = attn + ((size_t)(b * 1024 + qt * 64 + row)) * 2048 + h * 128 + d0;
#pragma unroll
  for (int j = 0; j < 4; j++) *(int4*)&dst[j * 8] = *(const int4*)&ob[j * 8];
}

extern "C" void kernel_launch(void* const* d_in, const int* in_sizes, int n_in,
                              void* d_out, int out_size, void* d_ws, size_t ws_size,
                              hipStream_t stream) {
  const float* x = (const float*)d_in[0];
  const float* cosb = (const float*)d_in[1];
  const float* sinb = (const float*)d_in[2];
  const float* mask = (const float*)d_in[3];
  const float* q_w = (const float*)d_in[4];
  const float* q_b = (const float*)d_in[5];
  const float* k_w = (const float*)d_in[6];
  const float* k_b = (const float*)d_in[7];
  const float* v_w = (const float*)d_in[8];
  const float* v_b = (const float*)d_in[9];
  const float* qg = (const float*)d_in[10];
  const float* kg = (const float*)d_in[11];
  const float* o_w = (const float*)d_in[12];
  float* out = (float*)d_out;

  char* ws = (char*)d_ws;
  // regions (MiB offsets), timeline-overlapped:
  // [0,8)   xb (dead after gemm1) ; [0,20) po (attn..combine) ; [0,16) pB (gemm2..addf)
  // [8,18)  wqkv_t (dead after gemm1)
  // [20,28) qb (gemm1..attn) ; then attn_out (combine..gemm2)
  // [28,29) kb ; [29,30) vb ; [30,31) vtb ; [31,39) wo_t ; [39,40) pml
  short* xb = (short*)(ws);
  short* po = (short*)(ws);
  float* pB = (float*)(ws);
  short* wqkv_t = (short*)(ws + ((size_t)8 << 20));
  short* qb = (short*)(ws + ((size_t)20 << 20));
  short* attn = qb;
  short* kb = (short*)(ws + ((size_t)28 << 20));
  short* vb = (short*)(ws + ((size_t)29 << 20));
  short* vtb = (short*)(ws + ((size_t)30 << 20));
  short* wo_t = (short*)(ws + ((size_t)31 << 20));
  float* pml = (float*)(ws + ((size_t)39 << 20));

  cvt_kernel<<<4096, 256, 0, stream>>>(x, xb, 2048 * 2048);
  tconv_all_kernel<<<2304, 256, 0, stream>>>(q_w, k_w, v_w, o_w, wqkv_t, wo_t);
  gemm_qkv_kernel<<<dim3(20, 16), 256, 0, stream>>>(xb, wqkv_t, q_b, k_b, v_b, qg, kg,
                                                    cosb, sinb, mask, qb, kb, vb);
  vtrans16_kernel<<<dim3(2, 16, 4), 256, 0, stream>>>(vb, vtb);
  attn_kernel<<<dim3(40, 16, 2), 256, 0, stream>>>(qb, kb, vtb, po, pml);
  attn_combine_kernel<<<dim3(16, 16, 2), 256, 0, stream>>>(po, pml, attn);
  gemm_kernel<<<dim3(16, 16, 2), 256, 0, stream>>>(attn, wo_t, out, pB, 2048, 2048, 2048,
                                                   1024);
  addf_kernel<<<4096, 256, 0, stream>>>(out, pB);
}

// Round 6
// 267.716 us; speedup vs baseline: 1.1499x; 1.1499x over previous
//
#include <hip/hip_runtime.h>

typedef __attribute__((ext_vector_type(8))) short bf16x8;
typedef __attribute__((ext_vector_type(4))) float f32x4;

#define MFMA16(a, b, c) __builtin_amdgcn_mfma_f32_16x16x32_bf16(a, b, c, 0, 0, 0)

__device__ inline short f2bf(float f) {
  union { float f; unsigned u; } v;
  v.f = f;
  unsigned r = v.u + 0x7FFF + ((v.u >> 16) & 1);
  return (short)(r >> 16);
}
__device__ inline float bf2f(short s) {
  union { unsigned u; float f; } v;
  v.u = ((unsigned)(unsigned short)s) << 16;
  return v.f;
}
#define GLD_LDS16(g, l)                                                        \
  __builtin_amdgcn_global_load_lds(                                            \
      (const __attribute__((address_space(1))) unsigned int*)(g),              \
      (__attribute__((address_space(3))) unsigned int*)(l), 16, 0, 0)

__device__ __forceinline__ void raw_barrier() {
  __asm__ volatile("" ::: "memory");
  __builtin_amdgcn_s_barrier();
  __asm__ volatile("" ::: "memory");
}

// ---------------- prep: x->bf16 convert + all 4 weight transposes, one launch ----------------
__global__ __launch_bounds__(256) void prep_kernel(
    const float* __restrict__ x, const float* __restrict__ q_w,
    const float* __restrict__ k_w, const float* __restrict__ v_w,
    const float* __restrict__ o_w, short* __restrict__ xb,
    short* __restrict__ wqkv_t, short* __restrict__ wo_t) {
  __shared__ float t[64][65];
  int bid = blockIdx.x;
  if (bid < 4096) {  // cvt x
    int i = (bid * 256 + threadIdx.x) * 4;
    float4 f = *(const float4*)&x[i];
    short4 o;
    o.x = f2bf(f.x); o.y = f2bf(f.y); o.z = f2bf(f.z); o.w = f2bf(f.w);
    *(short4*)&xb[i] = o;
    return;
  }
  bid -= 4096;
  const float* src;
  short* dst;
  int C, bx, by;
  if (bid < 1024) {
    src = q_w; dst = wqkv_t; C = 2048;
    bx = (bid & 31) * 64; by = (bid >> 5) * 64;
  } else if (bid < 1152) {
    bid -= 1024;
    src = k_w; dst = wqkv_t + (size_t)2048 * 2048; C = 256;
    bx = (bid & 3) * 64; by = (bid >> 2) * 64;
  } else if (bid < 1280) {
    bid -= 1152;
    src = v_w; dst = wqkv_t + (size_t)2304 * 2048; C = 256;
    bx = (bid & 3) * 64; by = (bid >> 2) * 64;
  } else {
    bid -= 1280;
    src = o_w; dst = wo_t; C = 2048;
    bx = (bid & 31) * 64; by = (bid >> 5) * 64;
  }
  const int R = 2048;
  const int tx = threadIdx.x & 15;
  const int ty = threadIdx.x >> 4;
#pragma unroll
  for (int i = 0; i < 4; i++) {
    int row = ty + i * 16;
    float4 f = *(const float4*)&src[(size_t)(by + row) * C + bx + tx * 4];
    t[row][tx * 4 + 0] = f.x;
    t[row][tx * 4 + 1] = f.y;
    t[row][tx * 4 + 2] = f.z;
    t[row][tx * 4 + 3] = f.w;
  }
  __syncthreads();
#pragma unroll
  for (int i = 0; i < 4; i++) {
    int c = ty + i * 16;
    short4 o;
    o.x = f2bf(t[tx * 4 + 0][c]);
    o.y = f2bf(t[tx * 4 + 1][c]);
    o.z = f2bf(t[tx * 4 + 2][c]);
    o.w = f2bf(t[tx * 4 + 3][c]);
    *(short4*)&dst[(size_t)(bx + c) * R + by + tx * 4] = o;
  }
}

// ---------------- bf16 GEMM, double-buffered LDS + fine-grained vmcnt pipeline --------------
// C(128x128 fp32 tile) = A(M x 2048 bf16) * B^T(N x 2048 bf16); K = 2048.
__global__ __launch_bounds__(256) void gemm_db_kernel(const short* __restrict__ A,
                                                      const short* __restrict__ B,
                                                      float* __restrict__ C, int N) {
  __shared__ __align__(16) short As[2][128 * 32];
  __shared__ __align__(16) short Bs[2][128 * 32];
  const int tid = threadIdx.x;
  const int lane = tid & 63, wave = tid >> 6;
  const int quad = lane >> 4, l16 = lane & 15;
  const int m0 = blockIdx.y * 128, n0 = blockIdx.x * 128;
  const int wm = (wave >> 1) * 64, wn = (wave & 1) * 64;
  f32x4 acc[4][4];
#pragma unroll
  for (int mi = 0; mi < 4; mi++)
#pragma unroll
    for (int ni = 0; ni < 4; ni++) acc[mi][ni] = (f32x4){0.f, 0.f, 0.f, 0.f};

  // prologue: stage k=0 into buf 0 (4 loads/thread)
#pragma unroll
  for (int it = 0; it < 2; it++) {
    int c = it * 256 + tid;
    int row = c >> 2, cc = (c & 3) * 8;
    GLD_LDS16(&A[(size_t)(m0 + row) * 2048 + cc], &As[0][c * 8]);
    GLD_LDS16(&B[(size_t)(n0 + row) * 2048 + cc], &Bs[0][c * 8]);
  }

  for (int k0 = 0; k0 < 2048; k0 += 32) {
    const int cur = (k0 >> 5) & 1;
    if (k0 + 32 < 2048) {
      // stage next tile into the other buffer (stays in flight through compute)
#pragma unroll
      for (int it = 0; it < 2; it++) {
        int c = it * 256 + tid;
        int row = c >> 2, cc = (c & 3) * 8;
        GLD_LDS16(&A[(size_t)(m0 + row) * 2048 + k0 + 32 + cc], &As[cur ^ 1][c * 8]);
        GLD_LDS16(&B[(size_t)(n0 + row) * 2048 + k0 + 32 + cc], &Bs[cur ^ 1][c * 8]);
      }
      // wait only for the CURRENT tile's 4 loads (issued last iter); next's 4 stay in flight
      __asm__ volatile("s_waitcnt vmcnt(4)" ::: "memory");
    } else {
      __asm__ volatile("s_waitcnt vmcnt(0)" ::: "memory");
    }
    raw_barrier();
    bf16x8 af[4], bfr[4];
#pragma unroll
    for (int mi = 0; mi < 4; mi++)
      af[mi] = *(const bf16x8*)&As[cur][(wm + mi * 16 + l16) * 32 + quad * 8];
#pragma unroll
    for (int ni = 0; ni < 4; ni++)
      bfr[ni] = *(const bf16x8*)&Bs[cur][(wn + ni * 16 + l16) * 32 + quad * 8];
#pragma unroll
    for (int mi = 0; mi < 4; mi++)
#pragma unroll
      for (int ni = 0; ni < 4; ni++)
        acc[mi][ni] = MFMA16(af[mi], bfr[ni], acc[mi][ni]);
    __asm__ volatile("s_waitcnt lgkmcnt(0)" ::: "memory");
    raw_barrier();
  }
#pragma unroll
  for (int mi = 0; mi < 4; mi++)
#pragma unroll
    for (int ni = 0; ni < 4; ni++)
#pragma unroll
      for (int r = 0; r < 4; r++)
        C[(size_t)(m0 + wm + mi * 16 + quad * 4 + r) * N + n0 + wn + ni * 16 + l16] =
            acc[mi][ni][r];
}

// ---------------- bias + rmsnorm + rope for Q,K: one wave per row ----------------
__global__ __launch_bounds__(256) void qkv_post_kernel(
    const float* __restrict__ qkv, const float* __restrict__ qbias,
    const float* __restrict__ kbias, const float* __restrict__ qg,
    const float* __restrict__ kg, const float* __restrict__ cosb,
    const float* __restrict__ sinb, const float* __restrict__ maskp,
    short* __restrict__ qo, short* __restrict__ ko) {
  const int rid = blockIdx.x * 4 + (threadIdx.x >> 6);
  const int lane = threadIdx.x & 63;
  const int slot = rid >> 11;
  const int bs = rid & 2047;
  const int b = bs >> 10, s = bs & 1023;
  const float* row = qkv + (size_t)bs * 2560;
  int off;
  const float* bias;
  const float* gamma;
  if (slot < 16) { off = slot * 128; bias = qbias + slot * 128; gamma = qg; }
  else { off = 2048 + (slot - 16) * 128; bias = kbias + (slot - 16) * 128; gamma = kg; }
  float v0 = row[off + lane] + bias[lane];
  float v1 = row[off + 64 + lane] + bias[64 + lane];
  float ss = v0 * v0 + v1 * v1;
#pragma unroll
  for (int o = 1; o < 64; o <<= 1) ss += __shfl_xor(ss, o);
  float r = rsqrtf(ss * (1.0f / 128.0f) + 1e-6f);
  v0 = gamma[lane] * v0 * r;
  v1 = gamma[64 + lane] * v1 * r;
  int sel = (lane < 16) ? 0 : (lane < 40) ? 1 : 2;
  size_t ci = ((size_t)(sel * 2 + b) * 1024 + s) * 128 + lane;
  float c0 = cosb[ci], s0 = sinb[ci], c1 = cosb[ci + 64], s1 = sinb[ci + 64];
  float o0 = v0 * c0 - v1 * s0;
  float o1 = v1 * c1 + v0 * s1;
  if (slot >= 16) { float mk = maskp[bs]; o0 *= mk; o1 *= mk; }
  size_t oidx;
  short* optr;
  if (slot < 16) { oidx = (((size_t)(b * 16 + slot) * 1024) + s) * 128; optr = qo; }
  else { oidx = (((size_t)(b * 2 + (slot - 16)) * 1024) + s) * 128; optr = ko; }
  optr[oidx + lane] = f2bf(o0);
  optr[oidx + 64 + lane] = f2bf(o1);
}

// ---------------- V: bias + mask + transpose -> (b,kv,d,s) bf16 ----------------
__global__ __launch_bounds__(256) void vtrans_kernel(const float* __restrict__ qkv,
                                                     const float* __restrict__ vbias,
                                                     const float* __restrict__ maskp,
                                                     short* __restrict__ vtb) {
  __shared__ short t[32][33];
  const int bz = blockIdx.z;
  const int bq = bz >> 1, kv = bz & 1;
  const int d0 = blockIdx.x * 32, s0 = blockIdx.y * 32;
  const int tx = threadIdx.x & 31;
  const int ty = threadIdx.x >> 5;
#pragma unroll
  for (int i = 0; i < 4; i++) {
    int s = s0 + ty + i * 8;
    float val = qkv[((size_t)(bq * 1024 + s)) * 2560 + 2304 + kv * 128 + d0 + tx] +
                vbias[kv * 128 + d0 + tx];
    t[ty + i * 8][tx] = f2bf(val * maskp[bq * 1024 + s]);
  }
  __syncthreads();
#pragma unroll
  for (int i = 0; i < 4; i++)
    vtb[((size_t)bz * 128 + d0 + ty + i * 8) * 1024 + s0 + tx] = t[tx][ty + i * 8];
}

// ---------------- flash attention, key-chunk split (chunk = 256 keys, <=4 steps) ----------------
__global__ __launch_bounds__(256) void attn_kernel(const short* __restrict__ Q,
                                                   const short* __restrict__ K,
                                                   const short* __restrict__ Vt_g,
                                                   short* __restrict__ po,
                                                   float* __restrict__ pml) {
  int x = blockIdx.x;
  const int h = blockIdx.y;
  const int b = blockIdx.z;
  int g = 0, base = 0;
  while (x >= base + 4 * (g + 1)) { base += 4 * (g + 1); g++; }
  const int r0 = x - base;
  const int qt = 4 * g + r0 / (g + 1);
  const int kc = r0 % (g + 1);
  int nsteps = qt - 4 * kc + 1;
  if (nsteps > 4) nsteps = 4;

  const int kv = h >> 3;
  const int tid = threadIdx.x;
  const int wave = tid >> 6, lane = tid & 63;
  const int quad = lane >> 4, l16 = lane & 15;
  __shared__ __align__(16) short Ks[64 * 136];
  __shared__ __align__(16) short Vs[128 * 72];
  __shared__ __align__(16) short Ps[4][16 * 68];

  const size_t qoff = (((size_t)(b * 16 + h) * 1024) + qt * 64 + wave * 16 + l16) * 128;
  bf16x8 aq[4];
#pragma unroll
  for (int kk = 0; kk < 4; kk++) aq[kk] = *(const bf16x8*)&Q[qoff + kk * 32 + quad * 8];

  f32x4 o[8];
#pragma unroll
  for (int i = 0; i < 8; i++) o[i] = (f32x4){0.f, 0.f, 0.f, 0.f};
  float m[4], l[4];
#pragma unroll
  for (int r = 0; r < 4; r++) { m[r] = -1e30f; l[r] = 0.f; }
  const int qrow0 = qt * 64 + wave * 16 + quad * 4;
  const size_t koff = ((size_t)(b * 2 + kv) * 1024) * 128;
  const size_t voff = koff;
  const float scale = 0.08838834764831845f;

  for (int st = 0; st < nsteps; st++) {
    const int ks0 = kc * 256 + st * 64;
#pragma unroll
    for (int it = 0; it < 4; it++) {
      int c = it * 256 + tid;
      {
        int row = c >> 4, cc = (c & 15) * 8;
        *(int4*)&Ks[row * 136 + cc] =
            *(const int4*)&K[koff + (size_t)(ks0 + row) * 128 + cc];
      }
      {
        int d = c >> 3, cc = (c & 7) * 8;
        *(int4*)&Vs[d * 72 + cc] =
            *(const int4*)&Vt_g[voff + (size_t)d * 1024 + ks0 + cc];
      }
    }
    __syncthreads();
    f32x4 sc[4];
#pragma unroll
    for (int nt = 0; nt < 4; nt++) sc[nt] = (f32x4){0.f, 0.f, 0.f, 0.f};
#pragma unroll
    for (int nt = 0; nt < 4; nt++)
#pragma unroll
      for (int kk = 0; kk < 4; kk++) {
        bf16x8 bk = *(const bf16x8*)&Ks[(nt * 16 + l16) * 136 + kk * 32 + quad * 8];
        sc[nt] = MFMA16(aq[kk], bk, sc[nt]);
      }
    float sv[4][4], mx[4];
#pragma unroll
    for (int r = 0; r < 4; r++) mx[r] = -1e30f;
#pragma unroll
    for (int nt = 0; nt < 4; nt++)
#pragma unroll
      for (int r = 0; r < 4; r++) {
        float s = sc[nt][r] * scale;
        int kcol = ks0 + nt * 16 + l16;
        if (kcol > qrow0 + r) s = -1e30f;
        sv[nt][r] = s;
        mx[r] = fmaxf(mx[r], s);
      }
#pragma unroll
    for (int off = 1; off < 16; off <<= 1)
#pragma unroll
      for (int r = 0; r < 4; r++) mx[r] = fmaxf(mx[r], __shfl_xor(mx[r], off));
    float alpha[4];
#pragma unroll
    for (int r = 0; r < 4; r++) {
      float mn = fmaxf(m[r], mx[r]);
      alpha[r] = __expf(m[r] - mn);
      m[r] = mn;
    }
    float rs[4] = {0.f, 0.f, 0.f, 0.f};
#pragma unroll
    for (int nt = 0; nt < 4; nt++)
#pragma unroll
      for (int r = 0; r < 4; r++) {
        float p = __expf(sv[nt][r] - m[r]);
        sv[nt][r] = p;
        rs[r] += p;
      }
#pragma unroll
    for (int r = 0; r < 4; r++) l[r] = l[r] * alpha[r] + rs[r];
#pragma unroll
    for (int i = 0; i < 8; i++)
#pragma unroll
      for (int r = 0; r < 4; r++) o[i][r] *= alpha[r];
    short* P = &Ps[wave][0];
#pragma unroll
    for (int nt = 0; nt < 4; nt++)
#pragma unroll
      for (int r = 0; r < 4; r++)
        P[(quad * 4 + r) * 68 + nt * 16 + l16] = f2bf(sv[nt][r]);
    __asm__ volatile("s_waitcnt lgkmcnt(0)" ::: "memory");
    bf16x8 pa0 = *(const bf16x8*)&P[l16 * 68 + quad * 8];
    bf16x8 pa1 = *(const bf16x8*)&P[l16 * 68 + 32 + quad * 8];
#pragma unroll
    for (int nt = 0; nt < 8; nt++) {
      bf16x8 bv0 = *(const bf16x8*)&Vs[(nt * 16 + l16) * 72 + quad * 8];
      bf16x8 bv1 = *(const bf16x8*)&Vs[(nt * 16 + l16) * 72 + 32 + quad * 8];
      o[nt] = MFMA16(pa0, bv0, o[nt]);
      o[nt] = MFMA16(pa1, bv1, o[nt]);
    }
    __syncthreads();
  }
#pragma unroll
  for (int off = 1; off < 16; off <<= 1)
#pragma unroll
    for (int r = 0; r < 4; r++) l[r] += __shfl_xor(l[r], off);
  const int p = (b * 16 + h) * 40 + blockIdx.x;
  const int lrow = wave * 16 + quad * 4;
#pragma unroll
  for (int nt = 0; nt < 8; nt++)
#pragma unroll
    for (int r = 0; r < 4; r++)
      po[(size_t)p * 8192 + (size_t)(lrow + r) * 128 + nt * 16 + l16] = f2bf(o[nt][r]);
  if (l16 == 0) {
#pragma unroll
    for (int r = 0; r < 4; r++) {
      pml[(size_t)p * 128 + lrow + r] = m[r];
      pml[(size_t)p * 128 + 64 + lrow + r] = l[r];
    }
  }
}

// ---------------- combine partials -> attn output (b*S, NH*HD) bf16 ----------------
__global__ __launch_bounds__(256) void attn_combine_kernel(const short* __restrict__ po,
                                                           const float* __restrict__ pml,
                                                           short* __restrict__ attn) {
  const int qt = blockIdx.x, h = blockIdx.y, b = blockIdx.z;
  const int g = qt >> 2, nc = g + 1;
  const int x0 = 2 * g * (g + 1) + (qt & 3) * nc;
  const int row = threadIdx.x >> 2;
  const int d0 = (threadIdx.x & 3) * 32;
  const int pbase = (b * 16 + h) * 40 + x0;
  float mm[4], ll[4], M = -1e30f;
#pragma unroll
  for (int kc = 0; kc < 4; kc++)
    if (kc < nc) {
      mm[kc] = pml[(size_t)(pbase + kc) * 128 + row];
      ll[kc] = pml[(size_t)(pbase + kc) * 128 + 64 + row];
      M = fmaxf(M, mm[kc]);
    }
  float denom = 0.f, sc[4];
#pragma unroll
  for (int kc = 0; kc < 4; kc++)
    if (kc < nc) { sc[kc] = __expf(mm[kc] - M); denom += sc[kc] * ll[kc]; }
  float inv = 1.f / denom;
  float acc[32];
#pragma unroll
  for (int j = 0; j < 32; j++) acc[j] = 0.f;
#pragma unroll
  for (int kc = 0; kc < 4; kc++)
    if (kc < nc) {
      const short* src = po + (size_t)(pbase + kc) * 8192 + (size_t)row * 128 + d0;
#pragma unroll
      for (int j = 0; j < 4; j++) {
        int4 v = *(const int4*)&src[j * 8];
        const short* vs = (const short*)&v;
#pragma unroll
        for (int e = 0; e < 8; e++) acc[j * 8 + e] += sc[kc] * bf2f(vs[e]);
      }
    }
  short ob[32];
#pragma unroll
  for (int j = 0; j < 32; j++) ob[j] = f2bf(acc[j] * inv);
  short* dst = attn + ((size_t)(b * 1024 + qt * 64 + row)) * 2048 + h * 128 + d0;
#pragma unroll
  for (int j = 0; j < 4; j++) *(int4*)&dst[j * 8] = *(const int4*)&ob[j * 8];
}

extern "C" void kernel_launch(void* const* d_in, const int* in_sizes, int n_in,
                              void* d_out, int out_size, void* d_ws, size_t ws_size,
                              hipStream_t stream) {
  const float* x = (const float*)d_in[0];
  const float* cosb = (const float*)d_in[1];
  const float* sinb = (const float*)d_in[2];
  const float* mask = (const float*)d_in[3];
  const float* q_w = (const float*)d_in[4];
  const float* q_b = (const float*)d_in[5];
  const float* k_w = (const float*)d_in[6];
  const float* k_b = (const float*)d_in[7];
  const float* v_w = (const float*)d_in[8];
  const float* v_b = (const float*)d_in[9];
  const float* qg = (const float*)d_in[10];
  const float* kg = (const float*)d_in[11];
  const float* o_w = (const float*)d_in[12];
  float* out = (float*)d_out;

  char* ws = (char*)d_ws;
  // MiB-offset regions, timeline-overlapped (peak 48):
  // [0,8)   wo_t           (prep .. gemm2)
  // [8,18)  wqkv_t         (prep .. gemm1);  [8,9) pml + [9,17) attn_out after gemm1
  // [18,26) xb             (prep .. gemm1);  qb after (post .. attn)
  // [26,46) qkv_raw        (gemm1 .. vtrans); po after (attn .. combine)
  // [46,47) kb ; [47,48) vtb                 (post/vtrans .. attn)
  short* wo_t = (short*)(ws);
  short* wqkv_t = (short*)(ws + ((size_t)8 << 20));
  float* pml = (float*)(ws + ((size_t)8 << 20));
  short* attn = (short*)(ws + ((size_t)9 << 20));
  short* xb = (short*)(ws + ((size_t)18 << 20));
  short* qb = xb;
  float* qkv_raw = (float*)(ws + ((size_t)26 << 20));
  short* po = (short*)(ws + ((size_t)26 << 20));
  short* kb = (short*)(ws + ((size_t)46 << 20));
  short* vtb = (short*)(ws + ((size_t)47 << 20));

  prep_kernel<<<6400, 256, 0, stream>>>(x, q_w, k_w, v_w, o_w, xb, wqkv_t, wo_t);
  gemm_db_kernel<<<dim3(20, 16), 256, 0, stream>>>(xb, wqkv_t, qkv_raw, 2560);
  qkv_post_kernel<<<9216, 256, 0, stream>>>(qkv_raw, q_b, k_b, qg, kg, cosb, sinb, mask,
                                            qb, kb);
  vtrans_kernel<<<dim3(4, 32, 4), 256, 0, stream>>>(qkv_raw, v_b, mask, vtb);
  attn_kernel<<<dim3(40, 16, 2), 256, 0, stream>>>(qb, kb, vtb, po, pml);
  attn_combine_kernel<<<dim3(16, 16, 2), 256, 0, stream>>>(po, pml, attn);
  gemm_db_kernel<<<dim3(16, 16), 256, 0, stream>>>(attn, wo_t, out, 2048);
}

// Round 7
// 263.749 us; speedup vs baseline: 1.1672x; 1.0150x over previous
//
#include <hip/hip_runtime.h>

typedef __attribute__((ext_vector_type(8))) short bf16x8;
typedef __attribute__((ext_vector_type(4))) float f32x4;

#define MFMA16(a, b, c) __builtin_amdgcn_mfma_f32_16x16x32_bf16(a, b, c, 0, 0, 0)

__device__ inline short f2bf(float f) {
  union { float f; unsigned u; } v;
  v.f = f;
  unsigned r = v.u + 0x7FFF + ((v.u >> 16) & 1);
  return (short)(r >> 16);
}
__device__ inline float bf2f(short s) {
  union { unsigned u; float f; } v;
  v.u = ((unsigned)(unsigned short)s) << 16;
  return v.f;
}
#define GLD_LDS16(g, l)                                                        \
  __builtin_amdgcn_global_load_lds(                                            \
      (const __attribute__((address_space(1))) unsigned int*)(g),              \
      (__attribute__((address_space(3))) unsigned int*)(l), 16, 0, 0)

__device__ __forceinline__ void raw_barrier() {
  __asm__ volatile("" ::: "memory");
  __builtin_amdgcn_s_barrier();
  __asm__ volatile("" ::: "memory");
}

// ---------------- prep: x->bf16 convert + all 4 weight transposes, one launch ----------------
__global__ __launch_bounds__(256) void prep_kernel(
    const float* __restrict__ x, const float* __restrict__ q_w,
    const float* __restrict__ k_w, const float* __restrict__ v_w,
    const float* __restrict__ o_w, short* __restrict__ xb,
    short* __restrict__ wqkv_t, short* __restrict__ wo_t) {
  __shared__ float t[64][65];
  int bid = blockIdx.x;
  if (bid < 4096) {  // cvt x
    int i = (bid * 256 + threadIdx.x) * 4;
    float4 f = *(const float4*)&x[i];
    short4 o;
    o.x = f2bf(f.x); o.y = f2bf(f.y); o.z = f2bf(f.z); o.w = f2bf(f.w);
    *(short4*)&xb[i] = o;
    return;
  }
  bid -= 4096;
  const float* src;
  short* dst;
  int C, bx, by;
  if (bid < 1024) {
    src = q_w; dst = wqkv_t; C = 2048;
    bx = (bid & 31) * 64; by = (bid >> 5) * 64;
  } else if (bid < 1152) {
    bid -= 1024;
    src = k_w; dst = wqkv_t + (size_t)2048 * 2048; C = 256;
    bx = (bid & 3) * 64; by = (bid >> 2) * 64;
  } else if (bid < 1280) {
    bid -= 1152;
    src = v_w; dst = wqkv_t + (size_t)2304 * 2048; C = 256;
    bx = (bid & 3) * 64; by = (bid >> 2) * 64;
  } else {
    bid -= 1280;
    src = o_w; dst = wo_t; C = 2048;
    bx = (bid & 31) * 64; by = (bid >> 5) * 64;
  }
  const int R = 2048;
  const int tx = threadIdx.x & 15;
  const int ty = threadIdx.x >> 4;
#pragma unroll
  for (int i = 0; i < 4; i++) {
    int row = ty + i * 16;
    float4 f = *(const float4*)&src[(size_t)(by + row) * C + bx + tx * 4];
    t[row][tx * 4 + 0] = f.x;
    t[row][tx * 4 + 1] = f.y;
    t[row][tx * 4 + 2] = f.z;
    t[row][tx * 4 + 3] = f.w;
  }
  __syncthreads();
#pragma unroll
  for (int i = 0; i < 4; i++) {
    int c = ty + i * 16;
    short4 o;
    o.x = f2bf(t[tx * 4 + 0][c]);
    o.y = f2bf(t[tx * 4 + 1][c]);
    o.z = f2bf(t[tx * 4 + 2][c]);
    o.w = f2bf(t[tx * 4 + 3][c]);
    *(short4*)&dst[(size_t)(bx + c) * R + by + tx * 4] = o;
  }
}

// ---------------- bf16 GEMM, depth-4 LDS pipeline, prefetch distance 3 ----------------
// C(128x128 fp32 tile) = A(M x 2048 bf16) * B^T(N x 2048 bf16); K = 2048 (64 stages).
__global__ __launch_bounds__(256) void gemm_db_kernel(const short* __restrict__ A,
                                                      const short* __restrict__ B,
                                                      float* __restrict__ C, int N) {
  __shared__ __align__(16) short As[4][128 * 32];
  __shared__ __align__(16) short Bs[4][128 * 32];
  const int tid = threadIdx.x;
  const int lane = tid & 63, wave = tid >> 6;
  const int quad = lane >> 4, l16 = lane & 15;
  const int m0 = blockIdx.y * 128, n0 = blockIdx.x * 128;
  const int wm = (wave >> 1) * 64, wn = (wave & 1) * 64;
  const int r0 = tid >> 2, c0 = (tid & 3) * 8;        // staging coords: rows r0, r0+64
  const size_t arow0 = (size_t)(m0 + r0) * 2048, arow1 = (size_t)(m0 + r0 + 64) * 2048;
  const size_t brow0 = (size_t)(n0 + r0) * 2048, brow1 = (size_t)(n0 + r0 + 64) * 2048;
  f32x4 acc[4][4];
#pragma unroll
  for (int mi = 0; mi < 4; mi++)
#pragma unroll
    for (int ni = 0; ni < 4; ni++) acc[mi][ni] = (f32x4){0.f, 0.f, 0.f, 0.f};

  // prologue: stage k-tiles 0,1,2
#pragma unroll
  for (int st = 0; st < 3; st++) {
    const int kk = st * 32 + c0;
    GLD_LDS16(&A[arow0 + kk], &As[st][r0 * 32 + c0]);
    GLD_LDS16(&A[arow1 + kk], &As[st][(r0 + 64) * 32 + c0]);
    GLD_LDS16(&B[brow0 + kk], &Bs[st][r0 * 32 + c0]);
    GLD_LDS16(&B[brow1 + kk], &Bs[st][(r0 + 64) * 32 + c0]);
  }

  for (int ki = 0; ki < 64; ki++) {
    const int cur = ki & 3;
    if (ki < 61) {
      const int nxt = (ki + 3) & 3;
      const int kk = (ki + 3) * 32 + c0;
      GLD_LDS16(&A[arow0 + kk], &As[nxt][r0 * 32 + c0]);
      GLD_LDS16(&A[arow1 + kk], &As[nxt][(r0 + 64) * 32 + c0]);
      GLD_LDS16(&B[brow0 + kk], &Bs[nxt][r0 * 32 + c0]);
      GLD_LDS16(&B[brow1 + kk], &Bs[nxt][(r0 + 64) * 32 + c0]);
      __asm__ volatile("s_waitcnt vmcnt(12)" ::: "memory");
    } else if (ki == 61) {
      __asm__ volatile("s_waitcnt vmcnt(8)" ::: "memory");
    } else if (ki == 62) {
      __asm__ volatile("s_waitcnt vmcnt(4)" ::: "memory");
    } else {
      __asm__ volatile("s_waitcnt vmcnt(0)" ::: "memory");
    }
    raw_barrier();
    bf16x8 af[4], bfr[4];
#pragma unroll
    for (int mi = 0; mi < 4; mi++)
      af[mi] = *(const bf16x8*)&As[cur][(wm + mi * 16 + l16) * 32 + quad * 8];
#pragma unroll
    for (int ni = 0; ni < 4; ni++)
      bfr[ni] = *(const bf16x8*)&Bs[cur][(wn + ni * 16 + l16) * 32 + quad * 8];
#pragma unroll
    for (int mi = 0; mi < 4; mi++)
#pragma unroll
      for (int ni = 0; ni < 4; ni++)
        acc[mi][ni] = MFMA16(af[mi], bfr[ni], acc[mi][ni]);
    __asm__ volatile("s_waitcnt lgkmcnt(0)" ::: "memory");
    raw_barrier();
  }
#pragma unroll
  for (int mi = 0; mi < 4; mi++)
#pragma unroll
    for (int ni = 0; ni < 4; ni++)
#pragma unroll
      for (int r = 0; r < 4; r++)
        C[(size_t)(m0 + wm + mi * 16 + quad * 4 + r) * N + n0 + wn + ni * 16 + l16] =
            acc[mi][ni][r];
}

// ---------------- bias + rmsnorm + rope for Q,K: one wave per row ----------------
__global__ __launch_bounds__(256) void qkv_post_kernel(
    const float* __restrict__ qkv, const float* __restrict__ qbias,
    const float* __restrict__ kbias, const float* __restrict__ qg,
    const float* __restrict__ kg, const float* __restrict__ cosb,
    const float* __restrict__ sinb, const float* __restrict__ maskp,
    short* __restrict__ qo, short* __restrict__ ko) {
  const int rid = blockIdx.x * 4 + (threadIdx.x >> 6);
  const int lane = threadIdx.x & 63;
  const int slot = rid >> 11;
  const int bs = rid & 2047;
  const int b = bs >> 10, s = bs & 1023;
  const float* row = qkv + (size_t)bs * 2560;
  int off;
  const float* bias;
  const float* gamma;
  if (slot < 16) { off = slot * 128; bias = qbias + slot * 128; gamma = qg; }
  else { off = 2048 + (slot - 16) * 128; bias = kbias + (slot - 16) * 128; gamma = kg; }
  float v0 = row[off + lane] + bias[lane];
  float v1 = row[off + 64 + lane] + bias[64 + lane];
  float ss = v0 * v0 + v1 * v1;
#pragma unroll
  for (int o = 1; o < 64; o <<= 1) ss += __shfl_xor(ss, o);
  float r = rsqrtf(ss * (1.0f / 128.0f) + 1e-6f);
  v0 = gamma[lane] * v0 * r;
  v1 = gamma[64 + lane] * v1 * r;
  int sel = (lane < 16) ? 0 : (lane < 40) ? 1 : 2;
  size_t ci = ((size_t)(sel * 2 + b) * 1024 + s) * 128 + lane;
  float c0 = cosb[ci], s0 = sinb[ci], c1 = cosb[ci + 64], s1 = sinb[ci + 64];
  float o0 = v0 * c0 - v1 * s0;
  float o1 = v1 * c1 + v0 * s1;
  if (slot >= 16) { float mk = maskp[bs]; o0 *= mk; o1 *= mk; }
  size_t oidx;
  short* optr;
  if (slot < 16) { oidx = (((size_t)(b * 16 + slot) * 1024) + s) * 128; optr = qo; }
  else { oidx = (((size_t)(b * 2 + (slot - 16)) * 1024) + s) * 128; optr = ko; }
  optr[oidx + lane] = f2bf(o0);
  optr[oidx + 64 + lane] = f2bf(o1);
}

// ---------------- V: bias + mask + transpose -> (b,kv,d,s) bf16 ----------------
__global__ __launch_bounds__(256) void vtrans_kernel(const float* __restrict__ qkv,
                                                     const float* __restrict__ vbias,
                                                     const float* __restrict__ maskp,
                                                     short* __restrict__ vtb) {
  __shared__ short t[32][33];
  const int bz = blockIdx.z;
  const int bq = bz >> 1, kv = bz & 1;
  const int d0 = blockIdx.x * 32, s0 = blockIdx.y * 32;
  const int tx = threadIdx.x & 31;
  const int ty = threadIdx.x >> 5;
#pragma unroll
  for (int i = 0; i < 4; i++) {
    int s = s0 + ty + i * 8;
    float val = qkv[((size_t)(bq * 1024 + s)) * 2560 + 2304 + kv * 128 + d0 + tx] +
                vbias[kv * 128 + d0 + tx];
    t[ty + i * 8][tx] = f2bf(val * maskp[bq * 1024 + s]);
  }
  __syncthreads();
#pragma unroll
  for (int i = 0; i < 4; i++)
    vtb[((size_t)bz * 128 + d0 + ty + i * 8) * 1024 + s0 + tx] = t[tx][ty + i * 8];
}

// ---------------- flash attention, key-chunk split (chunk = 256 keys, <=4 steps) ----------------
__global__ __launch_bounds__(256) void attn_kernel(const short* __restrict__ Q,
                                                   const short* __restrict__ K,
                                                   const short* __restrict__ Vt_g,
                                                   short* __restrict__ po,
                                                   float* __restrict__ pml) {
  int x = blockIdx.x;
  const int h = blockIdx.y;
  const int b = blockIdx.z;
  int g = 0, base = 0;
  while (x >= base + 4 * (g + 1)) { base += 4 * (g + 1); g++; }
  const int r0 = x - base;
  const int qt = 4 * g + r0 / (g + 1);
  const int kc = r0 % (g + 1);
  int nsteps = qt - 4 * kc + 1;
  if (nsteps > 4) nsteps = 4;

  const int kv = h >> 3;
  const int tid = threadIdx.x;
  const int wave = tid >> 6, lane = tid & 63;
  const int quad = lane >> 4, l16 = lane & 15;
  __shared__ __align__(16) short Ks[64 * 136];
  __shared__ __align__(16) short Vs[128 * 72];
  __shared__ __align__(16) short Ps[4][16 * 68];

  const size_t qoff = (((size_t)(b * 16 + h) * 1024) + qt * 64 + wave * 16 + l16) * 128;
  bf16x8 aq[4];
#pragma unroll
  for (int kk = 0; kk < 4; kk++) aq[kk] = *(const bf16x8*)&Q[qoff + kk * 32 + quad * 8];

  f32x4 o[8];
#pragma unroll
  for (int i = 0; i < 8; i++) o[i] = (f32x4){0.f, 0.f, 0.f, 0.f};
  float m[4], l[4];
#pragma unroll
  for (int r = 0; r < 4; r++) { m[r] = -1e30f; l[r] = 0.f; }
  const int qrow0 = qt * 64 + wave * 16 + quad * 4;
  const size_t koff = ((size_t)(b * 2 + kv) * 1024) * 128;
  const size_t voff = koff;
  const float scale = 0.08838834764831845f;

  for (int st = 0; st < nsteps; st++) {
    const int ks0 = kc * 256 + st * 64;
#pragma unroll
    for (int it = 0; it < 4; it++) {
      int c = it * 256 + tid;
      {
        int row = c >> 4, cc = (c & 15) * 8;
        *(int4*)&Ks[row * 136 + cc] =
            *(const int4*)&K[koff + (size_t)(ks0 + row) * 128 + cc];
      }
      {
        int d = c >> 3, cc = (c & 7) * 8;
        *(int4*)&Vs[d * 72 + cc] =
            *(const int4*)&Vt_g[voff + (size_t)d * 1024 + ks0 + cc];
      }
    }
    __syncthreads();
    f32x4 sc[4];
#pragma unroll
    for (int nt = 0; nt < 4; nt++) sc[nt] = (f32x4){0.f, 0.f, 0.f, 0.f};
#pragma unroll
    for (int nt = 0; nt < 4; nt++)
#pragma unroll
      for (int kk = 0; kk < 4; kk++) {
        bf16x8 bk = *(const bf16x8*)&Ks[(nt * 16 + l16) * 136 + kk * 32 + quad * 8];
        sc[nt] = MFMA16(aq[kk], bk, sc[nt]);
      }
    float sv[4][4], mx[4];
#pragma unroll
    for (int r = 0; r < 4; r++) mx[r] = -1e30f;
#pragma unroll
    for (int nt = 0; nt < 4; nt++)
#pragma unroll
      for (int r = 0; r < 4; r++) {
        float s = sc[nt][r] * scale;
        int kcol = ks0 + nt * 16 + l16;
        if (kcol > qrow0 + r) s = -1e30f;
        sv[nt][r] = s;
        mx[r] = fmaxf(mx[r], s);
      }
#pragma unroll
    for (int off = 1; off < 16; off <<= 1)
#pragma unroll
      for (int r = 0; r < 4; r++) mx[r] = fmaxf(mx[r], __shfl_xor(mx[r], off));
    float alpha[4];
#pragma unroll
    for (int r = 0; r < 4; r++) {
      float mn = fmaxf(m[r], mx[r]);
      alpha[r] = __expf(m[r] - mn);
      m[r] = mn;
    }
    float rs[4] = {0.f, 0.f, 0.f, 0.f};
#pragma unroll
    for (int nt = 0; nt < 4; nt++)
#pragma unroll
      for (int r = 0; r < 4; r++) {
        float p = __expf(sv[nt][r] - m[r]);
        sv[nt][r] = p;
        rs[r] += p;
      }
#pragma unroll
    for (int r = 0; r < 4; r++) l[r] = l[r] * alpha[r] + rs[r];
#pragma unroll
    for (int i = 0; i < 8; i++)
#pragma unroll
      for (int r = 0; r < 4; r++) o[i][r] *= alpha[r];
    short* P = &Ps[wave][0];
#pragma unroll
    for (int nt = 0; nt < 4; nt++)
#pragma unroll
      for (int r = 0; r < 4; r++)
        P[(quad * 4 + r) * 68 + nt * 16 + l16] = f2bf(sv[nt][r]);
    __asm__ volatile("s_waitcnt lgkmcnt(0)" ::: "memory");
    bf16x8 pa0 = *(const bf16x8*)&P[l16 * 68 + quad * 8];
    bf16x8 pa1 = *(const bf16x8*)&P[l16 * 68 + 32 + quad * 8];
#pragma unroll
    for (int nt = 0; nt < 8; nt++) {
      bf16x8 bv0 = *(const bf16x8*)&Vs[(nt * 16 + l16) * 72 + quad * 8];
      bf16x8 bv1 = *(const bf16x8*)&Vs[(nt * 16 + l16) * 72 + 32 + quad * 8];
      o[nt] = MFMA16(pa0, bv0, o[nt]);
      o[nt] = MFMA16(pa1, bv1, o[nt]);
    }
    __syncthreads();
  }
#pragma unroll
  for (int off = 1; off < 16; off <<= 1)
#pragma unroll
    for (int r = 0; r < 4; r++) l[r] += __shfl_xor(l[r], off);
  const int p = (b * 16 + h) * 40 + blockIdx.x;
  const int lrow = wave * 16 + quad * 4;
#pragma unroll
  for (int nt = 0; nt < 8; nt++)
#pragma unroll
    for (int r = 0; r < 4; r++)
      po[(size_t)p * 8192 + (size_t)(lrow + r) * 128 + nt * 16 + l16] = f2bf(o[nt][r]);
  if (l16 == 0) {
#pragma unroll
    for (int r = 0; r < 4; r++) {
      pml[(size_t)p * 128 + lrow + r] = m[r];
      pml[(size_t)p * 128 + 64 + lrow + r] = l[r];
    }
  }
}

// ---------------- combine partials -> attn output (b*S, NH*HD) bf16 ----------------
__global__ __launch_bounds__(256) void attn_combine_kernel(const short* __restrict__ po,
                                                           const float* __restrict__ pml,
                                                           short* __restrict__ attn) {
  const int qt = blockIdx.x, h = blockIdx.y, b = blockIdx.z;
  const int g = qt >> 2, nc = g + 1;
  const int x0 = 2 * g * (g + 1) + (qt & 3) * nc;
  const int row = threadIdx.x >> 2;
  const int d0 = (threadIdx.x & 3) * 32;
  const int pbase = (b * 16 + h) * 40 + x0;
  float mm[4], ll[4], M = -1e30f;
#pragma unroll
  for (int kc = 0; kc < 4; kc++)
    if (kc < nc) {
      mm[kc] = pml[(size_t)(pbase + kc) * 128 + row];
      ll[kc] = pml[(size_t)(pbase + kc) * 128 + 64 + row];
      M = fmaxf(M, mm[kc]);
    }
  float denom = 0.f, sc[4];
#pragma unroll
  for (int kc = 0; kc < 4; kc++)
    if (kc < nc) { sc[kc] = __expf(mm[kc] - M); denom += sc[kc] * ll[kc]; }
  float inv = 1.f / denom;
  float acc[32];
#pragma unroll
  for (int j = 0; j < 32; j++) acc[j] = 0.f;
#pragma unroll
  for (int kc = 0; kc < 4; kc++)
    if (kc < nc) {
      const short* src = po + (size_t)(pbase + kc) * 8192 + (size_t)row * 128 + d0;
#pragma unroll
      for (int j = 0; j < 4; j++) {
        int4 v = *(const int4*)&src[j * 8];
        const short* vs = (const short*)&v;
#pragma unroll
        for (int e = 0; e < 8; e++) acc[j * 8 + e] += sc[kc] * bf2f(vs[e]);
      }
    }
  short ob[32];
#pragma unroll
  for (int j = 0; j < 32; j++) ob[j] = f2bf(acc[j] * inv);
  short* dst = attn + ((size_t)(b * 1024 + qt * 64 + row)) * 2048 + h * 128 + d0;
#pragma unroll
  for (int j = 0; j < 4; j++) *(int4*)&dst[j * 8] = *(const int4*)&ob[j * 8];
}

extern "C" void kernel_launch(void* const* d_in, const int* in_sizes, int n_in,
                              void* d_out, int out_size, void* d_ws, size_t ws_size,
                              hipStream_t stream) {
  const float* x = (const float*)d_in[0];
  const float* cosb = (const float*)d_in[1];
  const float* sinb = (const float*)d_in[2];
  const float* mask = (const float*)d_in[3];
  const float* q_w = (const float*)d_in[4];
  const float* q_b = (const float*)d_in[5];
  const float* k_w = (const float*)d_in[6];
  const float* k_b = (const float*)d_in[7];
  const float* v_w = (const float*)d_in[8];
  const float* v_b = (const float*)d_in[9];
  const float* qg = (const float*)d_in[10];
  const float* kg = (const float*)d_in[11];
  const float* o_w = (const float*)d_in[12];
  float* out = (float*)d_out;

  char* ws = (char*)d_ws;
  // MiB-offset regions, timeline-overlapped (peak 48):
  short* wo_t = (short*)(ws);
  short* wqkv_t = (short*)(ws + ((size_t)8 << 20));
  float* pml = (float*)(ws + ((size_t)8 << 20));
  short* attn = (short*)(ws + ((size_t)9 << 20));
  short* xb = (short*)(ws + ((size_t)18 << 20));
  short* qb = xb;
  float* qkv_raw = (float*)(ws + ((size_t)26 << 20));
  short* po = (short*)(ws + ((size_t)26 << 20));
  short* kb = (short*)(ws + ((size_t)46 << 20));
  short* vtb = (short*)(ws + ((size_t)47 << 20));

  prep_kernel<<<6400, 256, 0, stream>>>(x, q_w, k_w, v_w, o_w, xb, wqkv_t, wo_t);
  gemm_db_kernel<<<dim3(20, 16), 256, 0, stream>>>(xb, wqkv_t, qkv_raw, 2560);
  qkv_post_kernel<<<9216, 256, 0, stream>>>(qkv_raw, q_b, k_b, qg, kg, cosb, sinb, mask,
                                            qb, kb);
  vtrans_kernel<<<dim3(4, 32, 4), 256, 0, stream>>>(qkv_raw, v_b, mask, vtb);
  attn_kernel<<<dim3(40, 16, 2), 256, 0, stream>>>(qb, kb, vtb, po, pml);
  attn_combine_kernel<<<dim3(16, 16, 2), 256, 0, stream>>>(po, pml, attn);
  gemm_db_kernel<<<dim3(16, 16), 256, 0, stream>>>(attn, wo_t, out, 2048);
}

// Round 8
// 253.328 us; speedup vs baseline: 1.2152x; 1.0411x over previous
//
#include <hip/hip_runtime.h>

typedef __attribute__((ext_vector_type(8))) short bf16x8;
typedef __attribute__((ext_vector_type(4))) float f32x4;

#define MFMA16(a, b, c) __builtin_amdgcn_mfma_f32_16x16x32_bf16(a, b, c, 0, 0, 0)

__device__ inline short f2bf(float f) {
  union { float f; unsigned u; } v;
  v.f = f;
  unsigned r = v.u + 0x7FFF + ((v.u >> 16) & 1);
  return (short)(r >> 16);
}
__device__ inline float bf2f(short s) {
  union { unsigned u; float f; } v;
  v.u = ((unsigned)(unsigned short)s) << 16;
  return v.f;
}
#define GLD_LDS16(g, l)                                                        \
  __builtin_amdgcn_global_load_lds(                                            \
      (const __attribute__((address_space(1))) unsigned int*)(g),              \
      (__attribute__((address_space(3))) unsigned int*)(l), 16, 0, 0)

__device__ __forceinline__ void raw_barrier() {
  __asm__ volatile("" ::: "memory");
  __builtin_amdgcn_s_barrier();
  __asm__ volatile("" ::: "memory");
}

// ---------------- prep: x->bf16 convert + all 4 weight transposes, one launch ----------------
__global__ __launch_bounds__(256) void prep_kernel(
    const float* __restrict__ x, const float* __restrict__ q_w,
    const float* __restrict__ k_w, const float* __restrict__ v_w,
    const float* __restrict__ o_w, short* __restrict__ xb,
    short* __restrict__ wqkv_t, short* __restrict__ wo_t) {
  __shared__ float t[64][65];
  int bid = blockIdx.x;
  if (bid < 4096) {  // cvt x
    int i = (bid * 256 + threadIdx.x) * 4;
    float4 f = *(const float4*)&x[i];
    short4 o;
    o.x = f2bf(f.x); o.y = f2bf(f.y); o.z = f2bf(f.z); o.w = f2bf(f.w);
    *(short4*)&xb[i] = o;
    return;
  }
  bid -= 4096;
  const float* src;
  short* dst;
  int C, bx, by;
  if (bid < 1024) {
    src = q_w; dst = wqkv_t; C = 2048;
    bx = (bid & 31) * 64; by = (bid >> 5) * 64;
  } else if (bid < 1152) {
    bid -= 1024;
    src = k_w; dst = wqkv_t + (size_t)2048 * 2048; C = 256;
    bx = (bid & 3) * 64; by = (bid >> 2) * 64;
  } else if (bid < 1280) {
    bid -= 1152;
    src = v_w; dst = wqkv_t + (size_t)2304 * 2048; C = 256;
    bx = (bid & 3) * 64; by = (bid >> 2) * 64;
  } else {
    bid -= 1280;
    src = o_w; dst = wo_t; C = 2048;
    bx = (bid & 31) * 64; by = (bid >> 5) * 64;
  }
  const int R = 2048;
  const int tx = threadIdx.x & 15;
  const int ty = threadIdx.x >> 4;
#pragma unroll
  for (int i = 0; i < 4; i++) {
    int row = ty + i * 16;
    float4 f = *(const float4*)&src[(size_t)(by + row) * C + bx + tx * 4];
    t[row][tx * 4 + 0] = f.x;
    t[row][tx * 4 + 1] = f.y;
    t[row][tx * 4 + 2] = f.z;
    t[row][tx * 4 + 3] = f.w;
  }
  __syncthreads();
#pragma unroll
  for (int i = 0; i < 4; i++) {
    int c = ty + i * 16;
    short4 o;
    o.x = f2bf(t[tx * 4 + 0][c]);
    o.y = f2bf(t[tx * 4 + 1][c]);
    o.z = f2bf(t[tx * 4 + 2][c]);
    o.w = f2bf(t[tx * 4 + 3][c]);
    *(short4*)&dst[(size_t)(bx + c) * R + by + tx * 4] = o;
  }
}

// ---------------- bf16 GEMM, 4-slot ring, pair-loop (BK=64 per barrier window) ----------------
// C(128x128 fp32 tile) = A(M x 2048 bf16) * B^T(N x 2048 bf16); K = 2048 (64 stages, 32 pairs).
__global__ __launch_bounds__(256) void gemm_db_kernel(const short* __restrict__ A,
                                                      const short* __restrict__ B,
                                                      float* __restrict__ C, int N) {
  __shared__ __align__(16) short As[4][128 * 32];
  __shared__ __align__(16) short Bs[4][128 * 32];
  const int tid = threadIdx.x;
  const int lane = tid & 63, wave = tid >> 6;
  const int quad = lane >> 4, l16 = lane & 15;
  const int m0 = blockIdx.y * 128, n0 = blockIdx.x * 128;
  const int wm = (wave >> 1) * 64, wn = (wave & 1) * 64;
  const int r0 = tid >> 2, c0 = (tid & 3) * 8;  // staging coords: rows r0, r0+64
  const size_t arow0 = (size_t)(m0 + r0) * 2048, arow1 = (size_t)(m0 + r0 + 64) * 2048;
  const size_t brow0 = (size_t)(n0 + r0) * 2048, brow1 = (size_t)(n0 + r0 + 64) * 2048;
  f32x4 acc[4][4];
#pragma unroll
  for (int mi = 0; mi < 4; mi++)
#pragma unroll
    for (int ni = 0; ni < 4; ni++) acc[mi][ni] = (f32x4){0.f, 0.f, 0.f, 0.f};

  // prologue: stage k-tiles 0..3 (pairs 0 and 1); 16 loads outstanding
#pragma unroll
  for (int st = 0; st < 4; st++) {
    const int kk = st * 32 + c0;
    GLD_LDS16(&A[arow0 + kk], &As[st][r0 * 32 + c0]);
    GLD_LDS16(&A[arow1 + kk], &As[st][(r0 + 64) * 32 + c0]);
    GLD_LDS16(&B[brow0 + kk], &Bs[st][r0 * 32 + c0]);
    GLD_LDS16(&B[brow1 + kk], &Bs[st][(r0 + 64) * 32 + c0]);
  }

  for (int p = 0; p < 32; p++) {
    if (p < 31) {
      __asm__ volatile("s_waitcnt vmcnt(8)" ::: "memory");  // pair p done; p+1 in flight
    } else {
      __asm__ volatile("s_waitcnt vmcnt(0)" ::: "memory");
    }
    raw_barrier();
#pragma unroll
    for (int j = 0; j < 2; j++) {
      const int cur = (2 * p + j) & 3;
      bf16x8 af[4], bfr[4];
#pragma unroll
      for (int mi = 0; mi < 4; mi++)
        af[mi] = *(const bf16x8*)&As[cur][(wm + mi * 16 + l16) * 32 + quad * 8];
#pragma unroll
      for (int ni = 0; ni < 4; ni++)
        bfr[ni] = *(const bf16x8*)&Bs[cur][(wn + ni * 16 + l16) * 32 + quad * 8];
#pragma unroll
      for (int mi = 0; mi < 4; mi++)
#pragma unroll
        for (int ni = 0; ni < 4; ni++)
          acc[mi][ni] = MFMA16(af[mi], bfr[ni], acc[mi][ni]);
    }
    __asm__ volatile("s_waitcnt lgkmcnt(0)" ::: "memory");
    raw_barrier();
    if (p < 30) {
      // issue pair p+2 into the slots pair p just vacated
#pragma unroll
      for (int j = 0; j < 2; j++) {
        const int st = 2 * p + 4 + j;
        const int slot = st & 3;
        const int kk = st * 32 + c0;
        GLD_LDS16(&A[arow0 + kk], &As[slot][r0 * 32 + c0]);
        GLD_LDS16(&A[arow1 + kk], &As[slot][(r0 + 64) * 32 + c0]);
        GLD_LDS16(&B[brow0 + kk], &Bs[slot][r0 * 32 + c0]);
        GLD_LDS16(&B[brow1 + kk], &Bs[slot][(r0 + 64) * 32 + c0]);
      }
    }
  }
#pragma unroll
  for (int mi = 0; mi < 4; mi++)
#pragma unroll
    for (int ni = 0; ni < 4; ni++)
#pragma unroll
      for (int r = 0; r < 4; r++)
        C[(size_t)(m0 + wm + mi * 16 + quad * 4 + r) * N + n0 + wn + ni * 16 + l16] =
            acc[mi][ni][r];
}

// ---------------- merged: Q/K post (bias+rmsnorm+rope+mask) AND V bias+mask+transpose ------
__global__ __launch_bounds__(256) void postv_kernel(
    const float* __restrict__ qkv, const float* __restrict__ qbias,
    const float* __restrict__ kbias, const float* __restrict__ vbias,
    const float* __restrict__ qg, const float* __restrict__ kg,
    const float* __restrict__ cosb, const float* __restrict__ sinb,
    const float* __restrict__ maskp, short* __restrict__ qo, short* __restrict__ ko,
    short* __restrict__ vtb) {
  __shared__ short t[32][33];
  const int bid = blockIdx.x;
  if (bid < 9216) {  // ---- Q/K post, one wave per row ----
    const int rid = bid * 4 + (threadIdx.x >> 6);
    const int lane = threadIdx.x & 63;
    const int slot = rid >> 11;
    const int bs = rid & 2047;
    const int b = bs >> 10, s = bs & 1023;
    const float* row = qkv + (size_t)bs * 2560;
    int off;
    const float* bias;
    const float* gamma;
    if (slot < 16) { off = slot * 128; bias = qbias + slot * 128; gamma = qg; }
    else { off = 2048 + (slot - 16) * 128; bias = kbias + (slot - 16) * 128; gamma = kg; }
    float v0 = row[off + lane] + bias[lane];
    float v1 = row[off + 64 + lane] + bias[64 + lane];
    float ss = v0 * v0 + v1 * v1;
#pragma unroll
    for (int o = 1; o < 64; o <<= 1) ss += __shfl_xor(ss, o);
    float r = rsqrtf(ss * (1.0f / 128.0f) + 1e-6f);
    v0 = gamma[lane] * v0 * r;
    v1 = gamma[64 + lane] * v1 * r;
    int sel = (lane < 16) ? 0 : (lane < 40) ? 1 : 2;
    size_t ci = ((size_t)(sel * 2 + b) * 1024 + s) * 128 + lane;
    float c0 = cosb[ci], s0 = sinb[ci], c1 = cosb[ci + 64], s1 = sinb[ci + 64];
    float o0 = v0 * c0 - v1 * s0;
    float o1 = v1 * c1 + v0 * s1;
    if (slot >= 16) { float mk = maskp[bs]; o0 *= mk; o1 *= mk; }
    size_t oidx;
    short* optr;
    if (slot < 16) { oidx = (((size_t)(b * 16 + slot) * 1024) + s) * 128; optr = qo; }
    else { oidx = (((size_t)(b * 2 + (slot - 16)) * 1024) + s) * 128; optr = ko; }
    optr[oidx + lane] = f2bf(o0);
    optr[oidx + 64 + lane] = f2bf(o1);
    return;
  }
  // ---- V: bias + mask + transpose -> (b,kv,d,s) bf16 ----
  const int b2 = bid - 9216;
  const int d0 = (b2 & 3) * 32;
  const int s0 = ((b2 >> 2) & 31) * 32;
  const int bz = b2 >> 7;  // b*2+kv
  const int bq = bz >> 1, kv = bz & 1;
  const int tx = threadIdx.x & 31;
  const int ty = threadIdx.x >> 5;
#pragma unroll
  for (int i = 0; i < 4; i++) {
    int s = s0 + ty + i * 8;
    float val = qkv[((size_t)(bq * 1024 + s)) * 2560 + 2304 + kv * 128 + d0 + tx] +
                vbias[kv * 128 + d0 + tx];
    t[ty + i * 8][tx] = f2bf(val * maskp[bq * 1024 + s]);
  }
  __syncthreads();
#pragma unroll
  for (int i = 0; i < 4; i++)
    vtb[((size_t)bz * 128 + d0 + ty + i * 8) * 1024 + s0 + tx] = t[tx][ty + i * 8];
}

// ---------------- flash attention, key-chunk split (chunk = 256 keys, <=4 steps) ----------------
__global__ __launch_bounds__(256) void attn_kernel(const short* __restrict__ Q,
                                                   const short* __restrict__ K,
                                                   const short* __restrict__ Vt_g,
                                                   short* __restrict__ po,
                                                   float* __restrict__ pml) {
  int x = blockIdx.x;
  const int h = blockIdx.y;
  const int b = blockIdx.z;
  int g = 0, base = 0;
  while (x >= base + 4 * (g + 1)) { base += 4 * (g + 1); g++; }
  const int r0 = x - base;
  const int qt = 4 * g + r0 / (g + 1);
  const int kc = r0 % (g + 1);
  int nsteps = qt - 4 * kc + 1;
  if (nsteps > 4) nsteps = 4;

  const int kv = h >> 3;
  const int tid = threadIdx.x;
  const int wave = tid >> 6, lane = tid & 63;
  const int quad = lane >> 4, l16 = lane & 15;
  __shared__ __align__(16) short Ks[64 * 136];
  __shared__ __align__(16) short Vs[128 * 72];
  __shared__ __align__(16) short Ps[4][16 * 68];

  const size_t qoff = (((size_t)(b * 16 + h) * 1024) + qt * 64 + wave * 16 + l16) * 128;
  bf16x8 aq[4];
#pragma unroll
  for (int kk = 0; kk < 4; kk++) aq[kk] = *(const bf16x8*)&Q[qoff + kk * 32 + quad * 8];

  f32x4 o[8];
#pragma unroll
  for (int i = 0; i < 8; i++) o[i] = (f32x4){0.f, 0.f, 0.f, 0.f};
  float m[4], l[4];
#pragma unroll
  for (int r = 0; r < 4; r++) { m[r] = -1e30f; l[r] = 0.f; }
  const int qrow0 = qt * 64 + wave * 16 + quad * 4;
  const size_t koff = ((size_t)(b * 2 + kv) * 1024) * 128;
  const size_t voff = koff;
  const float scale = 0.08838834764831845f;

  for (int st = 0; st < nsteps; st++) {
    const int ks0 = kc * 256 + st * 64;
#pragma unroll
    for (int it = 0; it < 4; it++) {
      int c = it * 256 + tid;
      {
        int row = c >> 4, cc = (c & 15) * 8;
        *(int4*)&Ks[row * 136 + cc] =
            *(const int4*)&K[koff + (size_t)(ks0 + row) * 128 + cc];
      }
      {
        int d = c >> 3, cc = (c & 7) * 8;
        *(int4*)&Vs[d * 72 + cc] =
            *(const int4*)&Vt_g[voff + (size_t)d * 1024 + ks0 + cc];
      }
    }
    __syncthreads();
    f32x4 sc[4];
#pragma unroll
    for (int nt = 0; nt < 4; nt++) sc[nt] = (f32x4){0.f, 0.f, 0.f, 0.f};
#pragma unroll
    for (int nt = 0; nt < 4; nt++)
#pragma unroll
      for (int kk = 0; kk < 4; kk++) {
        bf16x8 bk = *(const bf16x8*)&Ks[(nt * 16 + l16) * 136 + kk * 32 + quad * 8];
        sc[nt] = MFMA16(aq[kk], bk, sc[nt]);
      }
    float sv[4][4], mx[4];
#pragma unroll
    for (int r = 0; r < 4; r++) mx[r] = -1e30f;
#pragma unroll
    for (int nt = 0; nt < 4; nt++)
#pragma unroll
      for (int r = 0; r < 4; r++) {
        float s = sc[nt][r] * scale;
        int kcol = ks0 + nt * 16 + l16;
        if (kcol > qrow0 + r) s = -1e30f;
        sv[nt][r] = s;
        mx[r] = fmaxf(mx[r], s);
      }
#pragma unroll
    for (int off = 1; off < 16; off <<= 1)
#pragma unroll
      for (int r = 0; r < 4; r++) mx[r] = fmaxf(mx[r], __shfl_xor(mx[r], off));
    float alpha[4];
#pragma unroll
    for (int r = 0; r < 4; r++) {
      float mn = fmaxf(m[r], mx[r]);
      alpha[r] = __expf(m[r] - mn);
      m[r] = mn;
    }
    float rs[4] = {0.f, 0.f, 0.f, 0.f};
#pragma unroll
    for (int nt = 0; nt < 4; nt++)
#pragma unroll
      for (int r = 0; r < 4; r++) {
        float p = __expf(sv[nt][r] - m[r]);
        sv[nt][r] = p;
        rs[r] += p;
      }
#pragma unroll
    for (int r = 0; r < 4; r++) l[r] = l[r] * alpha[r] + rs[r];
#pragma unroll
    for (int i = 0; i < 8; i++)
#pragma unroll
      for (int r = 0; r < 4; r++) o[i][r] *= alpha[r];
    short* P = &Ps[wave][0];
#pragma unroll
    for (int nt = 0; nt < 4; nt++)
#pragma unroll
      for (int r = 0; r < 4; r++)
        P[(quad * 4 + r) * 68 + nt * 16 + l16] = f2bf(sv[nt][r]);
    __asm__ volatile("s_waitcnt lgkmcnt(0)" ::: "memory");
    bf16x8 pa0 = *(const bf16x8*)&P[l16 * 68 + quad * 8];
    bf16x8 pa1 = *(const bf16x8*)&P[l16 * 68 + 32 + quad * 8];
#pragma unroll
    for (int nt = 0; nt < 8; nt++) {
      bf16x8 bv0 = *(const bf16x8*)&Vs[(nt * 16 + l16) * 72 + quad * 8];
      bf16x8 bv1 = *(const bf16x8*)&Vs[(nt * 16 + l16) * 72 + 32 + quad * 8];
      o[nt] = MFMA16(pa0, bv0, o[nt]);
      o[nt] = MFMA16(pa1, bv1, o[nt]);
    }
    __syncthreads();
  }
#pragma unroll
  for (int off = 1; off < 16; off <<= 1)
#pragma unroll
    for (int r = 0; r < 4; r++) l[r] += __shfl_xor(l[r], off);
  const int p = (b * 16 + h) * 40 + blockIdx.x;
  const int lrow = wave * 16 + quad * 4;
#pragma unroll
  for (int nt = 0; nt < 8; nt++)
#pragma unroll
    for (int r = 0; r < 4; r++)
      po[(size_t)p * 8192 + (size_t)(lrow + r) * 128 + nt * 16 + l16] = f2bf(o[nt][r]);
  if (l16 == 0) {
#pragma unroll
    for (int r = 0; r < 4; r++) {
      pml[(size_t)p * 128 + lrow + r] = m[r];
      pml[(size_t)p * 128 + 64 + lrow + r] = l[r];
    }
  }
}

// ---------------- combine partials -> attn output (b*S, NH*HD) bf16 ----------------
__global__ __launch_bounds__(256) void attn_combine_kernel(const short* __restrict__ po,
                                                           const float* __restrict__ pml,
                                                           short* __restrict__ attn) {
  const int qt = blockIdx.x, h = blockIdx.y, b = blockIdx.z;
  const int g = qt >> 2, nc = g + 1;
  const int x0 = 2 * g * (g + 1) + (qt & 3) * nc;
  const int row = threadIdx.x >> 2;
  const int d0 = (threadIdx.x & 3) * 32;
  const int pbase = (b * 16 + h) * 40 + x0;
  float mm[4], ll[4], M = -1e30f;
#pragma unroll
  for (int kc = 0; kc < 4; kc++)
    if (kc < nc) {
      mm[kc] = pml[(size_t)(pbase + kc) * 128 + row];
      ll[kc] = pml[(size_t)(pbase + kc) * 128 + 64 + row];
      M = fmaxf(M, mm[kc]);
    }
  float denom = 0.f, sc[4];
#pragma unroll
  for (int kc = 0; kc < 4; kc++)
    if (kc < nc) { sc[kc] = __expf(mm[kc] - M); denom += sc[kc] * ll[kc]; }
  float inv = 1.f / denom;
  float acc[32];
#pragma unroll
  for (int j = 0; j < 32; j++) acc[j] = 0.f;
#pragma unroll
  for (int kc = 0; kc < 4; kc++)
    if (kc < nc) {
      const short* src = po + (size_t)(pbase + kc) * 8192 + (size_t)row * 128 + d0;
#pragma unroll
      for (int j = 0; j < 4; j++) {
        int4 v = *(const int4*)&src[j * 8];
        const short* vs = (const short*)&v;
#pragma unroll
        for (int e = 0; e < 8; e++) acc[j * 8 + e] += sc[kc] * bf2f(vs[e]);
      }
    }
  short ob[32];
#pragma unroll
  for (int j = 0; j < 32; j++) ob[j] = f2bf(acc[j] * inv);
  short* dst = attn + ((size_t)(b * 1024 + qt * 64 + row)) * 2048 + h * 128 + d0;
#pragma unroll
  for (int j = 0; j < 4; j++) *(int4*)&dst[j * 8] = *(const int4*)&ob[j * 8];
}

extern "C" void kernel_launch(void* const* d_in, const int* in_sizes, int n_in,
                              void* d_out, int out_size, void* d_ws, size_t ws_size,
                              hipStream_t stream) {
  const float* x = (const float*)d_in[0];
  const float* cosb = (const float*)d_in[1];
  const float* sinb = (const float*)d_in[2];
  const float* mask = (const float*)d_in[3];
  const float* q_w = (const float*)d_in[4];
  const float* q_b = (const float*)d_in[5];
  const float* k_w = (const float*)d_in[6];
  const float* k_b = (const float*)d_in[7];
  const float* v_w = (const float*)d_in[8];
  const float* v_b = (const float*)d_in[9];
  const float* qg = (const float*)d_in[10];
  const float* kg = (const float*)d_in[11];
  const float* o_w = (const float*)d_in[12];
  float* out = (float*)d_out;

  char* ws = (char*)d_ws;
  // MiB-offset regions, timeline-overlapped (peak 48):
  short* wo_t = (short*)(ws);
  short* wqkv_t = (short*)(ws + ((size_t)8 << 20));
  float* pml = (float*)(ws + ((size_t)8 << 20));
  short* attn = (short*)(ws + ((size_t)9 << 20));
  short* xb = (short*)(ws + ((size_t)18 << 20));
  short* qb = xb;
  float* qkv_raw = (float*)(ws + ((size_t)26 << 20));
  short* po = (short*)(ws + ((size_t)26 << 20));
  short* kb = (short*)(ws + ((size_t)46 << 20));
  short* vtb = (short*)(ws + ((size_t)47 << 20));

  prep_kernel<<<6400, 256, 0, stream>>>(x, q_w, k_w, v_w, o_w, xb, wqkv_t, wo_t);
  gemm_db_kernel<<<dim3(20, 16), 256, 0, stream>>>(xb, wqkv_t, qkv_raw, 2560);
  postv_kernel<<<9728, 256, 0, stream>>>(qkv_raw, q_b, k_b, v_b, qg, kg, cosb, sinb, mask,
                                         qb, kb, vtb);
  attn_kernel<<<dim3(40, 16, 2), 256, 0, stream>>>(qb, kb, vtb, po, pml);
  attn_combine_kernel<<<dim3(16, 16, 2), 256, 0, stream>>>(po, pml, attn);
  gemm_db_kernel<<<dim3(16, 16), 256, 0, stream>>>(attn, wo_t, out, 2048);
}

// Round 9
// 247.964 us; speedup vs baseline: 1.2415x; 1.0216x over previous
//
#include <hip/hip_runtime.h>

typedef __attribute__((ext_vector_type(8))) short bf16x8;
typedef __attribute__((ext_vector_type(4))) float f32x4;

#define MFMA16(a, b, c) __builtin_amdgcn_mfma_f32_16x16x32_bf16(a, b, c, 0, 0, 0)

__device__ inline short f2bf(float f) {
  union { float f; unsigned u; } v;
  v.f = f;
  unsigned r = v.u + 0x7FFF + ((v.u >> 16) & 1);
  return (short)(r >> 16);
}
__device__ inline float bf2f(short s) {
  union { unsigned u; float f; } v;
  v.u = ((unsigned)(unsigned short)s) << 16;
  return v.f;
}
#define GLD_LDS16(g, l)                                                        \
  __builtin_amdgcn_global_load_lds(                                            \
      (const __attribute__((address_space(1))) unsigned int*)(g),              \
      (__attribute__((address_space(3))) unsigned int*)(l), 16, 0, 0)

__device__ __forceinline__ void raw_barrier() {
  __asm__ volatile("" ::: "memory");
  __builtin_amdgcn_s_barrier();
  __asm__ volatile("" ::: "memory");
}

// ---------------- prep: x->bf16 convert + all 4 weight transposes, one launch ----------------
__global__ __launch_bounds__(256) void prep_kernel(
    const float* __restrict__ x, const float* __restrict__ q_w,
    const float* __restrict__ k_w, const float* __restrict__ v_w,
    const float* __restrict__ o_w, short* __restrict__ xb,
    short* __restrict__ wqkv_t, short* __restrict__ wo_t) {
  __shared__ float t[64][65];
  int bid = blockIdx.x;
  if (bid < 4096) {  // cvt x
    int i = (bid * 256 + threadIdx.x) * 4;
    float4 f = *(const float4*)&x[i];
    short4 o;
    o.x = f2bf(f.x); o.y = f2bf(f.y); o.z = f2bf(f.z); o.w = f2bf(f.w);
    *(short4*)&xb[i] = o;
    return;
  }
  bid -= 4096;
  const float* src;
  short* dst;
  int C, bx, by;
  if (bid < 1024) {
    src = q_w; dst = wqkv_t; C = 2048;
    bx = (bid & 31) * 64; by = (bid >> 5) * 64;
  } else if (bid < 1152) {
    bid -= 1024;
    src = k_w; dst = wqkv_t + (size_t)2048 * 2048; C = 256;
    bx = (bid & 3) * 64; by = (bid >> 2) * 64;
  } else if (bid < 1280) {
    bid -= 1152;
    src = v_w; dst = wqkv_t + (size_t)2304 * 2048; C = 256;
    bx = (bid & 3) * 64; by = (bid >> 2) * 64;
  } else {
    bid -= 1280;
    src = o_w; dst = wo_t; C = 2048;
    bx = (bid & 31) * 64; by = (bid >> 5) * 64;
  }
  const int R = 2048;
  const int tx = threadIdx.x & 15;
  const int ty = threadIdx.x >> 4;
#pragma unroll
  for (int i = 0; i < 4; i++) {
    int row = ty + i * 16;
    float4 f = *(const float4*)&src[(size_t)(by + row) * C + bx + tx * 4];
    t[row][tx * 4 + 0] = f.x;
    t[row][tx * 4 + 1] = f.y;
    t[row][tx * 4 + 2] = f.z;
    t[row][tx * 4 + 3] = f.w;
  }
  __syncthreads();
#pragma unroll
  for (int i = 0; i < 4; i++) {
    int c = ty + i * 16;
    short4 o;
    o.x = f2bf(t[tx * 4 + 0][c]);
    o.y = f2bf(t[tx * 4 + 1][c]);
    o.z = f2bf(t[tx * 4 + 2][c]);
    o.w = f2bf(t[tx * 4 + 3][c]);
    *(short4*)&dst[(size_t)(bx + c) * R + by + tx * 4] = o;
  }
}

// ---------------- bf16 GEMM, 4-slot ring, pair-loop (BK=64 per barrier window) ----------------
__global__ __launch_bounds__(256) void gemm_db_kernel(const short* __restrict__ A,
                                                      const short* __restrict__ B,
                                                      float* __restrict__ C, int N) {
  __shared__ __align__(16) short As[4][128 * 32];
  __shared__ __align__(16) short Bs[4][128 * 32];
  const int tid = threadIdx.x;
  const int lane = tid & 63, wave = tid >> 6;
  const int quad = lane >> 4, l16 = lane & 15;
  const int m0 = blockIdx.y * 128, n0 = blockIdx.x * 128;
  const int wm = (wave >> 1) * 64, wn = (wave & 1) * 64;
  const int r0 = tid >> 2, c0 = (tid & 3) * 8;
  const size_t arow0 = (size_t)(m0 + r0) * 2048, arow1 = (size_t)(m0 + r0 + 64) * 2048;
  const size_t brow0 = (size_t)(n0 + r0) * 2048, brow1 = (size_t)(n0 + r0 + 64) * 2048;
  f32x4 acc[4][4];
#pragma unroll
  for (int mi = 0; mi < 4; mi++)
#pragma unroll
    for (int ni = 0; ni < 4; ni++) acc[mi][ni] = (f32x4){0.f, 0.f, 0.f, 0.f};

#pragma unroll
  for (int st = 0; st < 4; st++) {
    const int kk = st * 32 + c0;
    GLD_LDS16(&A[arow0 + kk], &As[st][r0 * 32 + c0]);
    GLD_LDS16(&A[arow1 + kk], &As[st][(r0 + 64) * 32 + c0]);
    GLD_LDS16(&B[brow0 + kk], &Bs[st][r0 * 32 + c0]);
    GLD_LDS16(&B[brow1 + kk], &Bs[st][(r0 + 64) * 32 + c0]);
  }

  for (int p = 0; p < 32; p++) {
    if (p < 31) {
      __asm__ volatile("s_waitcnt vmcnt(8)" ::: "memory");
    } else {
      __asm__ volatile("s_waitcnt vmcnt(0)" ::: "memory");
    }
    raw_barrier();
#pragma unroll
    for (int j = 0; j < 2; j++) {
      const int cur = (2 * p + j) & 3;
      bf16x8 af[4], bfr[4];
#pragma unroll
      for (int mi = 0; mi < 4; mi++)
        af[mi] = *(const bf16x8*)&As[cur][(wm + mi * 16 + l16) * 32 + quad * 8];
#pragma unroll
      for (int ni = 0; ni < 4; ni++)
        bfr[ni] = *(const bf16x8*)&Bs[cur][(wn + ni * 16 + l16) * 32 + quad * 8];
#pragma unroll
      for (int mi = 0; mi < 4; mi++)
#pragma unroll
        for (int ni = 0; ni < 4; ni++)
          acc[mi][ni] = MFMA16(af[mi], bfr[ni], acc[mi][ni]);
    }
    __asm__ volatile("s_waitcnt lgkmcnt(0)" ::: "memory");
    raw_barrier();
    if (p < 30) {
#pragma unroll
      for (int j = 0; j < 2; j++) {
        const int st = 2 * p + 4 + j;
        const int slot = st & 3;
        const int kk = st * 32 + c0;
        GLD_LDS16(&A[arow0 + kk], &As[slot][r0 * 32 + c0]);
        GLD_LDS16(&A[arow1 + kk], &As[slot][(r0 + 64) * 32 + c0]);
        GLD_LDS16(&B[brow0 + kk], &Bs[slot][r0 * 32 + c0]);
        GLD_LDS16(&B[brow1 + kk], &Bs[slot][(r0 + 64) * 32 + c0]);
      }
    }
  }
#pragma unroll
  for (int mi = 0; mi < 4; mi++)
#pragma unroll
    for (int ni = 0; ni < 4; ni++)
#pragma unroll
      for (int r = 0; r < 4; r++)
        C[(size_t)(m0 + wm + mi * 16 + quad * 4 + r) * N + n0 + wn + ni * 16 + l16] =
            acc[mi][ni][r];
}

// ---------------- merged: Q/K post (bias+rmsnorm+rope+mask) AND V bias+mask+transpose ------
__global__ __launch_bounds__(256) void postv_kernel(
    const float* __restrict__ qkv, const float* __restrict__ qbias,
    const float* __restrict__ kbias, const float* __restrict__ vbias,
    const float* __restrict__ qg, const float* __restrict__ kg,
    const float* __restrict__ cosb, const float* __restrict__ sinb,
    const float* __restrict__ maskp, short* __restrict__ qo, short* __restrict__ ko,
    short* __restrict__ vtb) {
  __shared__ short t[32][33];
  const int bid = blockIdx.x;
  if (bid < 9216) {
    const int rid = bid * 4 + (threadIdx.x >> 6);
    const int lane = threadIdx.x & 63;
    const int slot = rid >> 11;
    const int bs = rid & 2047;
    const int b = bs >> 10, s = bs & 1023;
    const float* row = qkv + (size_t)bs * 2560;
    int off;
    const float* bias;
    const float* gamma;
    if (slot < 16) { off = slot * 128; bias = qbias + slot * 128; gamma = qg; }
    else { off = 2048 + (slot - 16) * 128; bias = kbias + (slot - 16) * 128; gamma = kg; }
    float v0 = row[off + lane] + bias[lane];
    float v1 = row[off + 64 + lane] + bias[64 + lane];
    float ss = v0 * v0 + v1 * v1;
#pragma unroll
    for (int o = 1; o < 64; o <<= 1) ss += __shfl_xor(ss, o);
    float r = rsqrtf(ss * (1.0f / 128.0f) + 1e-6f);
    v0 = gamma[lane] * v0 * r;
    v1 = gamma[64 + lane] * v1 * r;
    int sel = (lane < 16) ? 0 : (lane < 40) ? 1 : 2;
    size_t ci = ((size_t)(sel * 2 + b) * 1024 + s) * 128 + lane;
    float c0 = cosb[ci], s0 = sinb[ci], c1 = cosb[ci + 64], s1 = sinb[ci + 64];
    float o0 = v0 * c0 - v1 * s0;
    float o1 = v1 * c1 + v0 * s1;
    if (slot >= 16) { float mk = maskp[bs]; o0 *= mk; o1 *= mk; }
    size_t oidx;
    short* optr;
    if (slot < 16) { oidx = (((size_t)(b * 16 + slot) * 1024) + s) * 128; optr = qo; }
    else { oidx = (((size_t)(b * 2 + (slot - 16)) * 1024) + s) * 128; optr = ko; }
    optr[oidx + lane] = f2bf(o0);
    optr[oidx + 64 + lane] = f2bf(o1);
    return;
  }
  const int b2 = bid - 9216;
  const int d0 = (b2 & 3) * 32;
  const int s0 = ((b2 >> 2) & 31) * 32;
  const int bz = b2 >> 7;
  const int bq = bz >> 1, kv = bz & 1;
  const int tx = threadIdx.x & 31;
  const int ty = threadIdx.x >> 5;
#pragma unroll
  for (int i = 0; i < 4; i++) {
    int s = s0 + ty + i * 8;
    float val = qkv[((size_t)(bq * 1024 + s)) * 2560 + 2304 + kv * 128 + d0 + tx] +
                vbias[kv * 128 + d0 + tx];
    t[ty + i * 8][tx] = f2bf(val * maskp[bq * 1024 + s]);
  }
  __syncthreads();
#pragma unroll
  for (int i = 0; i < 4; i++)
    vtb[((size_t)bz * 128 + d0 + ty + i * 8) * 1024 + s0 + tx] = t[tx][ty + i * 8];
}

// ---------------- flash attention, key-chunk split, FIXED-SHIFT softmax ----------------
// |score| <= sqrt(128) = 11.32 (rmsnorm'd q,k; rope preserves norm) -> exp(s-12) safe.
__global__ __launch_bounds__(256) void attn_kernel(const short* __restrict__ Q,
                                                   const short* __restrict__ K,
                                                   const short* __restrict__ Vt_g,
                                                   short* __restrict__ po,
                                                   float* __restrict__ pml) {
  int x = blockIdx.x;
  const int h = blockIdx.y;
  const int b = blockIdx.z;
  int g = 0, base = 0;
  while (x >= base + 4 * (g + 1)) { base += 4 * (g + 1); g++; }
  const int r0 = x - base;
  const int qt = 4 * g + r0 / (g + 1);
  const int kc = r0 % (g + 1);
  int nsteps = qt - 4 * kc + 1;
  if (nsteps > 4) nsteps = 4;

  const int kv = h >> 3;
  const int tid = threadIdx.x;
  const int wave = tid >> 6, lane = tid & 63;
  const int quad = lane >> 4, l16 = lane & 15;
  __shared__ __align__(16) short Ks[64 * 136];
  __shared__ __align__(16) short Vs[128 * 72];
  __shared__ __align__(16) short Ps[4][16 * 68];

  const size_t qoff = (((size_t)(b * 16 + h) * 1024) + qt * 64 + wave * 16 + l16) * 128;
  bf16x8 aq[4];
#pragma unroll
  for (int kk = 0; kk < 4; kk++) aq[kk] = *(const bf16x8*)&Q[qoff + kk * 32 + quad * 8];

  f32x4 o[8];
#pragma unroll
  for (int i = 0; i < 8; i++) o[i] = (f32x4){0.f, 0.f, 0.f, 0.f};
  float l[4] = {0.f, 0.f, 0.f, 0.f};
  const int qrow0 = qt * 64 + wave * 16 + quad * 4;
  const size_t koff = ((size_t)(b * 2 + kv) * 1024) * 128;
  const size_t voff = koff;
  const float scale = 0.08838834764831845f;  // 1/sqrt(128)

  for (int st = 0; st < nsteps; st++) {
    const int ks0 = kc * 256 + st * 64;
#pragma unroll
    for (int it = 0; it < 4; it++) {
      int c = it * 256 + tid;
      {
        int row = c >> 4, cc = (c & 15) * 8;
        *(int4*)&Ks[row * 136 + cc] =
            *(const int4*)&K[koff + (size_t)(ks0 + row) * 128 + cc];
      }
      {
        int d = c >> 3, cc = (c & 7) * 8;
        *(int4*)&Vs[d * 72 + cc] =
            *(const int4*)&Vt_g[voff + (size_t)d * 1024 + ks0 + cc];
      }
    }
    __syncthreads();
    f32x4 sc[4];
#pragma unroll
    for (int nt = 0; nt < 4; nt++) sc[nt] = (f32x4){0.f, 0.f, 0.f, 0.f};
#pragma unroll
    for (int nt = 0; nt < 4; nt++)
#pragma unroll
      for (int kk = 0; kk < 4; kk++) {
        bf16x8 bk = *(const bf16x8*)&Ks[(nt * 16 + l16) * 136 + kk * 32 + quad * 8];
        sc[nt] = MFMA16(aq[kk], bk, sc[nt]);
      }
    // fixed-shift softmax weights: p = exp(s*scale - 12), causal-masked to 0
    short* P = &Ps[wave][0];
#pragma unroll
    for (int nt = 0; nt < 4; nt++) {
      const int kcol = ks0 + nt * 16 + l16;
#pragma unroll
      for (int r = 0; r < 4; r++) {
        float p = (kcol > qrow0 + r) ? 0.f : __expf(fmaf(sc[nt][r], scale, -12.0f));
        l[r] += p;
        P[(quad * 4 + r) * 68 + nt * 16 + l16] = f2bf(p);
      }
    }
    __asm__ volatile("s_waitcnt lgkmcnt(0)" ::: "memory");
    bf16x8 pa0 = *(const bf16x8*)&P[l16 * 68 + quad * 8];
    bf16x8 pa1 = *(const bf16x8*)&P[l16 * 68 + 32 + quad * 8];
#pragma unroll
    for (int nt = 0; nt < 8; nt++) {
      bf16x8 bv0 = *(const bf16x8*)&Vs[(nt * 16 + l16) * 72 + quad * 8];
      bf16x8 bv1 = *(const bf16x8*)&Vs[(nt * 16 + l16) * 72 + 32 + quad * 8];
      o[nt] = MFMA16(pa0, bv0, o[nt]);
      o[nt] = MFMA16(pa1, bv1, o[nt]);
    }
    __syncthreads();
  }
#pragma unroll
  for (int off = 1; off < 16; off <<= 1)
#pragma unroll
    for (int r = 0; r < 4; r++) l[r] += __shfl_xor(l[r], off);
  const int p = (b * 16 + h) * 40 + blockIdx.x;
  const int lrow = wave * 16 + quad * 4;
#pragma unroll
  for (int nt = 0; nt < 8; nt++)
#pragma unroll
    for (int r = 0; r < 4; r++)
      po[(size_t)p * 8192 + (size_t)(lrow + r) * 128 + nt * 16 + l16] = f2bf(o[nt][r]);
  if (l16 == 0) {
#pragma unroll
    for (int r = 0; r < 4; r++) pml[(size_t)p * 64 + lrow + r] = l[r];
  }
}

// ---------------- combine partials (shared fixed shift -> plain sums) ----------------
__global__ __launch_bounds__(256) void attn_combine_kernel(const short* __restrict__ po,
                                                           const float* __restrict__ pml,
                                                           short* __restrict__ attn) {
  const int qt = blockIdx.x, h = blockIdx.y, b = blockIdx.z;
  const int g = qt >> 2, nc = g + 1;
  const int x0 = 2 * g * (g + 1) + (qt & 3) * nc;
  const int row = threadIdx.x >> 2;
  const int d0 = (threadIdx.x & 3) * 32;
  const int pbase = (b * 16 + h) * 40 + x0;
  float denom = 0.f;
#pragma unroll
  for (int kc = 0; kc < 4; kc++)
    if (kc < nc) denom += pml[(size_t)(pbase + kc) * 64 + row];
  float inv = 1.f / denom;
  float acc[32];
#pragma unroll
  for (int j = 0; j < 32; j++) acc[j] = 0.f;
#pragma unroll
  for (int kc = 0; kc < 4; kc++)
    if (kc < nc) {
      const short* src = po + (size_t)(pbase + kc) * 8192 + (size_t)row * 128 + d0;
#pragma unroll
      for (int j = 0; j < 4; j++) {
        int4 v = *(const int4*)&src[j * 8];
        const short* vs = (const short*)&v;
#pragma unroll
        for (int e = 0; e < 8; e++) acc[j * 8 + e] += bf2f(vs[e]);
      }
    }
  short ob[32];
#pragma unroll
  for (int j = 0; j < 32; j++) ob[j] = f2bf(acc[j] * inv);
  short* dst = attn + ((size_t)(b * 1024 + qt * 64 + row)) * 2048 + h * 128 + d0;
#pragma unroll
  for (int j = 0; j < 4; j++) *(int4*)&dst[j * 8] = *(const int4*)&ob[j * 8];
}

extern "C" void kernel_launch(void* const* d_in, const int* in_sizes, int n_in,
                              void* d_out, int out_size, void* d_ws, size_t ws_size,
                              hipStream_t stream) {
  const float* x = (const float*)d_in[0];
  const float* cosb = (const float*)d_in[1];
  const float* sinb = (const float*)d_in[2];
  const float* mask = (const float*)d_in[3];
  const float* q_w = (const float*)d_in[4];
  const float* q_b = (const float*)d_in[5];
  const float* k_w = (const float*)d_in[6];
  const float* k_b = (const float*)d_in[7];
  const float* v_w = (const float*)d_in[8];
  const float* v_b = (const float*)d_in[9];
  const float* qg = (const float*)d_in[10];
  const float* kg = (const float*)d_in[11];
  const float* o_w = (const float*)d_in[12];
  float* out = (float*)d_out;

  char* ws = (char*)d_ws;
  short* wo_t = (short*)(ws);
  short* wqkv_t = (short*)(ws + ((size_t)8 << 20));
  float* pml = (float*)(ws + ((size_t)8 << 20));
  short* attn = (short*)(ws + ((size_t)9 << 20));
  short* xb = (short*)(ws + ((size_t)18 << 20));
  short* qb = xb;
  float* qkv_raw = (float*)(ws + ((size_t)26 << 20));
  short* po = (short*)(ws + ((size_t)26 << 20));
  short* kb = (short*)(ws + ((size_t)46 << 20));
  short* vtb = (short*)(ws + ((size_t)47 << 20));

  prep_kernel<<<6400, 256, 0, stream>>>(x, q_w, k_w, v_w, o_w, xb, wqkv_t, wo_t);
  gemm_db_kernel<<<dim3(20, 16), 256, 0, stream>>>(xb, wqkv_t, qkv_raw, 2560);
  postv_kernel<<<9728, 256, 0, stream>>>(qkv_raw, q_b, k_b, v_b, qg, kg, cosb, sinb, mask,
                                         qb, kb, vtb);
  attn_kernel<<<dim3(40, 16, 2), 256, 0, stream>>>(qb, kb, vtb, po, pml);
  attn_combine_kernel<<<dim3(16, 16, 2), 256, 0, stream>>>(po, pml, attn);
  gemm_db_kernel<<<dim3(16, 16), 256, 0, stream>>>(attn, wo_t, out, 2048);
}

// Round 10
// 246.145 us; speedup vs baseline: 1.2507x; 1.0074x over previous
//
#include <hip/hip_runtime.h>

typedef __attribute__((ext_vector_type(8))) short bf16x8;
typedef __attribute__((ext_vector_type(4))) float f32x4;

#define MFMA16(a, b, c) __builtin_amdgcn_mfma_f32_16x16x32_bf16(a, b, c, 0, 0, 0)

__device__ inline short f2bf(float f) {
  union { float f; unsigned u; } v;
  v.f = f;
  unsigned r = v.u + 0x7FFF + ((v.u >> 16) & 1);
  return (short)(r >> 16);
}
__device__ inline float bf2f(short s) {
  union { unsigned u; float f; } v;
  v.u = ((unsigned)(unsigned short)s) << 16;
  return v.f;
}
#define GLD_LDS16(g, l)                                                        \
  __builtin_amdgcn_global_load_lds(                                            \
      (const __attribute__((address_space(1))) unsigned int*)(g),              \
      (__attribute__((address_space(3))) unsigned int*)(l), 16, 0, 0)

__device__ __forceinline__ void raw_barrier() {
  __asm__ volatile("" ::: "memory");
  __builtin_amdgcn_s_barrier();
  __asm__ volatile("" ::: "memory");
}

// ---------------- prep: x->bf16 convert + all 4 weight transposes, one launch ----------------
__global__ __launch_bounds__(256) void prep_kernel(
    const float* __restrict__ x, const float* __restrict__ q_w,
    const float* __restrict__ k_w, const float* __restrict__ v_w,
    const float* __restrict__ o_w, short* __restrict__ xb,
    short* __restrict__ wqkv_t, short* __restrict__ wo_t) {
  __shared__ float t[64][65];
  int bid = blockIdx.x;
  if (bid < 4096) {  // cvt x
    int i = (bid * 256 + threadIdx.x) * 4;
    float4 f = *(const float4*)&x[i];
    short4 o;
    o.x = f2bf(f.x); o.y = f2bf(f.y); o.z = f2bf(f.z); o.w = f2bf(f.w);
    *(short4*)&xb[i] = o;
    return;
  }
  bid -= 4096;
  const float* src;
  short* dst;
  int C, bx, by;
  if (bid < 1024) {
    src = q_w; dst = wqkv_t; C = 2048;
    bx = (bid & 31) * 64; by = (bid >> 5) * 64;
  } else if (bid < 1152) {
    bid -= 1024;
    src = k_w; dst = wqkv_t + (size_t)2048 * 2048; C = 256;
    bx = (bid & 3) * 64; by = (bid >> 2) * 64;
  } else if (bid < 1280) {
    bid -= 1152;
    src = v_w; dst = wqkv_t + (size_t)2304 * 2048; C = 256;
    bx = (bid & 3) * 64; by = (bid >> 2) * 64;
  } else {
    bid -= 1280;
    src = o_w; dst = wo_t; C = 2048;
    bx = (bid & 31) * 64; by = (bid >> 5) * 64;
  }
  const int R = 2048;
  const int tx = threadIdx.x & 15;
  const int ty = threadIdx.x >> 4;
#pragma unroll
  for (int i = 0; i < 4; i++) {
    int row = ty + i * 16;
    float4 f = *(const float4*)&src[(size_t)(by + row) * C + bx + tx * 4];
    t[row][tx * 4 + 0] = f.x;
    t[row][tx * 4 + 1] = f.y;
    t[row][tx * 4 + 2] = f.z;
    t[row][tx * 4 + 3] = f.w;
  }
  __syncthreads();
#pragma unroll
  for (int i = 0; i < 4; i++) {
    int c = ty + i * 16;
    short4 o;
    o.x = f2bf(t[tx * 4 + 0][c]);
    o.y = f2bf(t[tx * 4 + 1][c]);
    o.z = f2bf(t[tx * 4 + 2][c]);
    o.w = f2bf(t[tx * 4 + 3][c]);
    *(short4*)&dst[(size_t)(bx + c) * R + by + tx * 4] = o;
  }
}

// ---------------- bf16 GEMM, 4-slot ring, pair-loop, XCD-aware tile swizzle ----------------
// 1D grid of gx*gy blocks. bid%8 = XCD (HW round-robin): each XCD owns a contiguous
// (gx/2) x (gy/4) tile region so its L2 retains the thin A/B K-slices all its blocks share.
__global__ __launch_bounds__(256) void gemm_db_kernel(const short* __restrict__ A,
                                                      const short* __restrict__ B,
                                                      float* __restrict__ C, int N,
                                                      int gx, int gy) {
  __shared__ __align__(16) short As[4][128 * 32];
  __shared__ __align__(16) short Bs[4][128 * 32];
  const int bid = blockIdx.x;
  const int xcd = bid & 7, idx = bid >> 3;
  const int colsPerX = gx >> 1, rowsPerX = gy >> 2;
  const int xt = (xcd & 1) * colsPerX + idx % colsPerX;
  const int yt = (xcd >> 1) * rowsPerX + idx / colsPerX;
  const int tid = threadIdx.x;
  const int lane = tid & 63, wave = tid >> 6;
  const int quad = lane >> 4, l16 = lane & 15;
  const int m0 = yt * 128, n0 = xt * 128;
  const int wm = (wave >> 1) * 64, wn = (wave & 1) * 64;
  const int r0 = tid >> 2, c0 = (tid & 3) * 8;
  const size_t arow0 = (size_t)(m0 + r0) * 2048, arow1 = (size_t)(m0 + r0 + 64) * 2048;
  const size_t brow0 = (size_t)(n0 + r0) * 2048, brow1 = (size_t)(n0 + r0 + 64) * 2048;
  f32x4 acc[4][4];
#pragma unroll
  for (int mi = 0; mi < 4; mi++)
#pragma unroll
    for (int ni = 0; ni < 4; ni++) acc[mi][ni] = (f32x4){0.f, 0.f, 0.f, 0.f};

#pragma unroll
  for (int st = 0; st < 4; st++) {
    const int kk = st * 32 + c0;
    GLD_LDS16(&A[arow0 + kk], &As[st][r0 * 32 + c0]);
    GLD_LDS16(&A[arow1 + kk], &As[st][(r0 + 64) * 32 + c0]);
    GLD_LDS16(&B[brow0 + kk], &Bs[st][r0 * 32 + c0]);
    GLD_LDS16(&B[brow1 + kk], &Bs[st][(r0 + 64) * 32 + c0]);
  }

  for (int p = 0; p < 32; p++) {
    if (p < 31) {
      __asm__ volatile("s_waitcnt vmcnt(8)" ::: "memory");
    } else {
      __asm__ volatile("s_waitcnt vmcnt(0)" ::: "memory");
    }
    raw_barrier();
#pragma unroll
    for (int j = 0; j < 2; j++) {
      const int cur = (2 * p + j) & 3;
      bf16x8 af[4], bfr[4];
#pragma unroll
      for (int mi = 0; mi < 4; mi++)
        af[mi] = *(const bf16x8*)&As[cur][(wm + mi * 16 + l16) * 32 + quad * 8];
#pragma unroll
      for (int ni = 0; ni < 4; ni++)
        bfr[ni] = *(const bf16x8*)&Bs[cur][(wn + ni * 16 + l16) * 32 + quad * 8];
#pragma unroll
      for (int mi = 0; mi < 4; mi++)
#pragma unroll
        for (int ni = 0; ni < 4; ni++)
          acc[mi][ni] = MFMA16(af[mi], bfr[ni], acc[mi][ni]);
    }
    __asm__ volatile("s_waitcnt lgkmcnt(0)" ::: "memory");
    raw_barrier();
    if (p < 30) {
#pragma unroll
      for (int j = 0; j < 2; j++) {
        const int st = 2 * p + 4 + j;
        const int slot = st & 3;
        const int kk = st * 32 + c0;
        GLD_LDS16(&A[arow0 + kk], &As[slot][r0 * 32 + c0]);
        GLD_LDS16(&A[arow1 + kk], &As[slot][(r0 + 64) * 32 + c0]);
        GLD_LDS16(&B[brow0 + kk], &Bs[slot][r0 * 32 + c0]);
        GLD_LDS16(&B[brow1 + kk], &Bs[slot][(r0 + 64) * 32 + c0]);
      }
    }
  }
#pragma unroll
  for (int mi = 0; mi < 4; mi++)
#pragma unroll
    for (int ni = 0; ni < 4; ni++)
#pragma unroll
      for (int r = 0; r < 4; r++)
        C[(size_t)(m0 + wm + mi * 16 + quad * 4 + r) * N + n0 + wn + ni * 16 + l16] =
            acc[mi][ni][r];
}

// ---------------- merged: Q/K post (bias+rmsnorm+rope+mask) AND V bias+mask+transpose ------
__global__ __launch_bounds__(256) void postv_kernel(
    const float* __restrict__ qkv, const float* __restrict__ qbias,
    const float* __restrict__ kbias, const float* __restrict__ vbias,
    const float* __restrict__ qg, const float* __restrict__ kg,
    const float* __restrict__ cosb, const float* __restrict__ sinb,
    const float* __restrict__ maskp, short* __restrict__ qo, short* __restrict__ ko,
    short* __restrict__ vtb) {
  __shared__ short t[32][33];
  const int bid = blockIdx.x;
  if (bid < 9216) {
    const int rid = bid * 4 + (threadIdx.x >> 6);
    const int lane = threadIdx.x & 63;
    const int slot = rid >> 11;
    const int bs = rid & 2047;
    const int b = bs >> 10, s = bs & 1023;
    const float* row = qkv + (size_t)bs * 2560;
    int off;
    const float* bias;
    const float* gamma;
    if (slot < 16) { off = slot * 128; bias = qbias + slot * 128; gamma = qg; }
    else { off = 2048 + (slot - 16) * 128; bias = kbias + (slot - 16) * 128; gamma = kg; }
    float v0 = row[off + lane] + bias[lane];
    float v1 = row[off + 64 + lane] + bias[64 + lane];
    float ss = v0 * v0 + v1 * v1;
#pragma unroll
    for (int o = 1; o < 64; o <<= 1) ss += __shfl_xor(ss, o);
    float r = rsqrtf(ss * (1.0f / 128.0f) + 1e-6f);
    v0 = gamma[lane] * v0 * r;
    v1 = gamma[64 + lane] * v1 * r;
    int sel = (lane < 16) ? 0 : (lane < 40) ? 1 : 2;
    size_t ci = ((size_t)(sel * 2 + b) * 1024 + s) * 128 + lane;
    float c0 = cosb[ci], s0 = sinb[ci], c1 = cosb[ci + 64], s1 = sinb[ci + 64];
    float o0 = v0 * c0 - v1 * s0;
    float o1 = v1 * c1 + v0 * s1;
    if (slot >= 16) { float mk = maskp[bs]; o0 *= mk; o1 *= mk; }
    size_t oidx;
    short* optr;
    if (slot < 16) { oidx = (((size_t)(b * 16 + slot) * 1024) + s) * 128; optr = qo; }
    else { oidx = (((size_t)(b * 2 + (slot - 16)) * 1024) + s) * 128; optr = ko; }
    optr[oidx + lane] = f2bf(o0);
    optr[oidx + 64 + lane] = f2bf(o1);
    return;
  }
  const int b2 = bid - 9216;
  const int d0 = (b2 & 3) * 32;
  const int s0 = ((b2 >> 2) & 31) * 32;
  const int bz = b2 >> 7;
  const int bq = bz >> 1, kv = bz & 1;
  const int tx = threadIdx.x & 31;
  const int ty = threadIdx.x >> 5;
#pragma unroll
  for (int i = 0; i < 4; i++) {
    int s = s0 + ty + i * 8;
    float val = qkv[((size_t)(bq * 1024 + s)) * 2560 + 2304 + kv * 128 + d0 + tx] +
                vbias[kv * 128 + d0 + tx];
    t[ty + i * 8][tx] = f2bf(val * maskp[bq * 1024 + s]);
  }
  __syncthreads();
#pragma unroll
  for (int i = 0; i < 4; i++)
    vtb[((size_t)bz * 128 + d0 + ty + i * 8) * 1024 + s0 + tx] = t[tx][ty + i * 8];
}

// ---------------- flash attention, key-chunk split, FIXED-SHIFT softmax ----------------
// |score| <= sqrt(128) = 11.32 (rmsnorm'd q,k; rope preserves norm) -> exp(s-12) safe.
__global__ __launch_bounds__(256) void attn_kernel(const short* __restrict__ Q,
                                                   const short* __restrict__ K,
                                                   const short* __restrict__ Vt_g,
                                                   short* __restrict__ po,
                                                   float* __restrict__ pml) {
  int x = blockIdx.x;
  const int h = blockIdx.y;
  const int b = blockIdx.z;
  int g = 0, base = 0;
  while (x >= base + 4 * (g + 1)) { base += 4 * (g + 1); g++; }
  const int r0 = x - base;
  const int qt = 4 * g + r0 / (g + 1);
  const int kc = r0 % (g + 1);
  int nsteps = qt - 4 * kc + 1;
  if (nsteps > 4) nsteps = 4;

  const int kv = h >> 3;
  const int tid = threadIdx.x;
  const int wave = tid >> 6, lane = tid & 63;
  const int quad = lane >> 4, l16 = lane & 15;
  __shared__ __align__(16) short Ks[64 * 136];
  __shared__ __align__(16) short Vs[128 * 72];
  __shared__ __align__(16) short Ps[4][16 * 68];

  const size_t qoff = (((size_t)(b * 16 + h) * 1024) + qt * 64 + wave * 16 + l16) * 128;
  bf16x8 aq[4];
#pragma unroll
  for (int kk = 0; kk < 4; kk++) aq[kk] = *(const bf16x8*)&Q[qoff + kk * 32 + quad * 8];

  f32x4 o[8];
#pragma unroll
  for (int i = 0; i < 8; i++) o[i] = (f32x4){0.f, 0.f, 0.f, 0.f};
  float l[4] = {0.f, 0.f, 0.f, 0.f};
  const int qrow0 = qt * 64 + wave * 16 + quad * 4;
  const size_t koff = ((size_t)(b * 2 + kv) * 1024) * 128;
  const size_t voff = koff;
  const float scale = 0.08838834764831845f;  // 1/sqrt(128)

  for (int st = 0; st < nsteps; st++) {
    const int ks0 = kc * 256 + st * 64;
#pragma unroll
    for (int it = 0; it < 4; it++) {
      int c = it * 256 + tid;
      {
        int row = c >> 4, cc = (c & 15) * 8;
        *(int4*)&Ks[row * 136 + cc] =
            *(const int4*)&K[koff + (size_t)(ks0 + row) * 128 + cc];
      }
      {
        int d = c >> 3, cc = (c & 7) * 8;
        *(int4*)&Vs[d * 72 + cc] =
            *(const int4*)&Vt_g[voff + (size_t)d * 1024 + ks0 + cc];
      }
    }
    __syncthreads();
    f32x4 sc[4];
#pragma unroll
    for (int nt = 0; nt < 4; nt++) sc[nt] = (f32x4){0.f, 0.f, 0.f, 0.f};
#pragma unroll
    for (int nt = 0; nt < 4; nt++)
#pragma unroll
      for (int kk = 0; kk < 4; kk++) {
        bf16x8 bk = *(const bf16x8*)&Ks[(nt * 16 + l16) * 136 + kk * 32 + quad * 8];
        sc[nt] = MFMA16(aq[kk], bk, sc[nt]);
      }
    // fixed-shift softmax weights: p = exp(s*scale - 12), causal-masked to 0
    short* P = &Ps[wave][0];
#pragma unroll
    for (int nt = 0; nt < 4; nt++) {
      const int kcol = ks0 + nt * 16 + l16;
#pragma unroll
      for (int r = 0; r < 4; r++) {
        float p = (kcol > qrow0 + r) ? 0.f : __expf(fmaf(sc[nt][r], scale, -12.0f));
        l[r] += p;
        P[(quad * 4 + r) * 68 + nt * 16 + l16] = f2bf(p);
      }
    }
    __asm__ volatile("s_waitcnt lgkmcnt(0)" ::: "memory");
    bf16x8 pa0 = *(const bf16x8*)&P[l16 * 68 + quad * 8];
    bf16x8 pa1 = *(const bf16x8*)&P[l16 * 68 + 32 + quad * 8];
#pragma unroll
    for (int nt = 0; nt < 8; nt++) {
      bf16x8 bv0 = *(const bf16x8*)&Vs[(nt * 16 + l16) * 72 + quad * 8];
      bf16x8 bv1 = *(const bf16x8*)&Vs[(nt * 16 + l16) * 72 + 32 + quad * 8];
      o[nt] = MFMA16(pa0, bv0, o[nt]);
      o[nt] = MFMA16(pa1, bv1, o[nt]);
    }
    __syncthreads();
  }
#pragma unroll
  for (int off = 1; off < 16; off <<= 1)
#pragma unroll
    for (int r = 0; r < 4; r++) l[r] += __shfl_xor(l[r], off);
  const int p = (b * 16 + h) * 40 + blockIdx.x;
  const int lrow = wave * 16 + quad * 4;
#pragma unroll
  for (int nt = 0; nt < 8; nt++)
#pragma unroll
    for (int r = 0; r < 4; r++)
      po[(size_t)p * 8192 + (size_t)(lrow + r) * 128 + nt * 16 + l16] = f2bf(o[nt][r]);
  if (l16 == 0) {
#pragma unroll
    for (int r = 0; r < 4; r++) pml[(size_t)p * 64 + lrow + r] = l[r];
  }
}

// ---------------- combine partials (shared fixed shift -> plain sums) ----------------
__global__ __launch_bounds__(256) void attn_combine_kernel(const short* __restrict__ po,
                                                           const float* __restrict__ pml,
                                                           short* __restrict__ attn) {
  const int qt = blockIdx.x, h = blockIdx.y, b = blockIdx.z;
  const int g = qt >> 2, nc = g + 1;
  const int x0 = 2 * g * (g + 1) + (qt & 3) * nc;
  const int row = threadIdx.x >> 2;
  const int d0 = (threadIdx.x & 3) * 32;
  const int pbase = (b * 16 + h) * 40 + x0;
  float denom = 0.f;
#pragma unroll
  for (int kc = 0; kc < 4; kc++)
    if (kc < nc) denom += pml[(size_t)(pbase + kc) * 64 + row];
  float inv = 1.f / denom;
  float acc[32];
#pragma unroll
  for (int j = 0; j < 32; j++) acc[j] = 0.f;
#pragma unroll
  for (int kc = 0; kc < 4; kc++)
    if (kc < nc) {
      const short* src = po + (size_t)(pbase + kc) * 8192 + (size_t)row * 128 + d0;
#pragma unroll
      for (int j = 0; j < 4; j++) {
        int4 v = *(const int4*)&src[j * 8];
        const short* vs = (const short*)&v;
#pragma unroll
        for (int e = 0; e < 8; e++) acc[j * 8 + e] += bf2f(vs[e]);
      }
    }
  short ob[32];
#pragma unroll
  for (int j = 0; j < 32; j++) ob[j] = f2bf(acc[j] * inv);
  short* dst = attn + ((size_t)(b * 1024 + qt * 64 + row)) * 2048 + h * 128 + d0;
#pragma unroll
  for (int j = 0; j < 4; j++) *(int4*)&dst[j * 8] = *(const int4*)&ob[j * 8];
}

extern "C" void kernel_launch(void* const* d_in, const int* in_sizes, int n_in,
                              void* d_out, int out_size, void* d_ws, size_t ws_size,
                              hipStream_t stream) {
  const float* x = (const float*)d_in[0];
  const float* cosb = (const float*)d_in[1];
  const float* sinb = (const float*)d_in[2];
  const float* mask = (const float*)d_in[3];
  const float* q_w = (const float*)d_in[4];
  const float* q_b = (const float*)d_in[5];
  const float* k_w = (const float*)d_in[6];
  const float* k_b = (const float*)d_in[7];
  const float* v_w = (const float*)d_in[8];
  const float* v_b = (const float*)d_in[9];
  const float* qg = (const float*)d_in[10];
  const float* kg = (const float*)d_in[11];
  const float* o_w = (const float*)d_in[12];
  float* out = (float*)d_out;

  char* ws = (char*)d_ws;
  short* wo_t = (short*)(ws);
  short* wqkv_t = (short*)(ws + ((size_t)8 << 20));
  float* pml = (float*)(ws + ((size_t)8 << 20));
  short* attn = (short*)(ws + ((size_t)9 << 20));
  short* xb = (short*)(ws + ((size_t)18 << 20));
  short* qb = xb;
  float* qkv_raw = (float*)(ws + ((size_t)26 << 20));
  short* po = (short*)(ws + ((size_t)26 << 20));
  short* kb = (short*)(ws + ((size_t)46 << 20));
  short* vtb = (short*)(ws + ((size_t)47 << 20));

  prep_kernel<<<6400, 256, 0, stream>>>(x, q_w, k_w, v_w, o_w, xb, wqkv_t, wo_t);
  gemm_db_kernel<<<320, 256, 0, stream>>>(xb, wqkv_t, qkv_raw, 2560, 20, 16);
  postv_kernel<<<9728, 256, 0, stream>>>(qkv_raw, q_b, k_b, v_b, qg, kg, cosb, sinb, mask,
                                         qb, kb, vtb);
  attn_kernel<<<dim3(40, 16, 2), 256, 0, stream>>>(qb, kb, vtb, po, pml);
  attn_combine_kernel<<<dim3(16, 16, 2), 256, 0, stream>>>(po, pml, attn);
  gemm_db_kernel<<<256, 256, 0, stream>>>(attn, wo_t, out, 2048, 16, 16);
}